// Round 3
// baseline (197.282 us; speedup 1.0000x reference)
//
#include <hip/hip_runtime.h>
#include <math.h>

#define NB   4
#define NN   2048
#define DD   512
#define NOUT 512
#define NH   8
#define HDIM 64

typedef __attribute__((ext_vector_type(4))) short bf16x4;
typedef __attribute__((ext_vector_type(8))) short bf16x8;
typedef __attribute__((ext_vector_type(4))) float f32x4;
#define MFMA32(a, b, c)  __builtin_amdgcn_mfma_f32_16x16x32_bf16(a, b, c, 0, 0, 0)

typedef const __attribute__((address_space(1))) unsigned int* gas_ptr;
typedef __attribute__((address_space(3))) unsigned int* las_ptr;

#define SCALE2 0.18033688f   /* 8^-1 * log2(e) */

// Fragment-tiled layout: T[blk128][kstep32][row128][32k]
//   flat = blk*65536 + ks*4096 + r*32 + kk

__device__ inline unsigned short f2bf(float f) {
    unsigned int u = __float_as_uint(f);
    u += 0x7fffu + ((u >> 16) & 1u);   // RNE
    return (unsigned short)(u >> 16);
}

// pack two fp32 -> two bf16 (truncation) in ONE v_perm
__device__ inline unsigned int pack_trunc(float lo, float hi) {
    return __builtin_amdgcn_perm(__float_as_uint(hi), __float_as_uint(lo), 0x07060302u);
}

// ---------------------------------------------------------------------------
// prep: convx (x -> bf16, fragment-tiled), transW (weights -> bf16 transposed
// + tiled), amask (adj -> u32 AND-words: word w of row q = 0xFFFF per live
// key {2w,2w+1}).
// ---------------------------------------------------------------------------
__global__ __launch_bounds__(256) void prep(
    const float* __restrict__ x, unsigned short* __restrict__ xt,
    const float* __restrict__ W0, const float* __restrict__ W1,
    const float* __restrict__ W2, const float* __restrict__ W3,
    unsigned short* __restrict__ Tqkv, unsigned short* __restrict__ To,
    const int* __restrict__ adj, unsigned int* __restrict__ amaskW)
{
    const int blk = blockIdx.x;
    const int t   = threadIdx.x;

    if (blk < 2048) {                       // ---- convx -> tiled ----
        const int i = (blk * 256 + t) * 8;
        const int m = i >> 9, k = i & 511;
        float4 a = *(const float4*)(x + i);
        float4 b = *(const float4*)(x + i + 4);
        ushort4 u0, u1;
        u0.x = f2bf(a.x); u0.y = f2bf(a.y); u0.z = f2bf(a.z); u0.w = f2bf(a.w);
        u1.x = f2bf(b.x); u1.y = f2bf(b.y); u1.z = f2bf(b.z); u1.w = f2bf(b.w);
        unsigned short* dst = xt + ((size_t)(m >> 7) * 65536)
                                 + (k >> 5) * 4096 + (m & 127) * 32 + (k & 31);
        *(ushort4*)dst       = u0;
        *(ushort4*)(dst + 4) = u1;
        return;
    }
    if (blk < 2304) {                       // ---- transW -> tiled ----
        __shared__ float tile[64][65];
        const int idx = blk - 2048;
        const int z = idx >> 6, rem = idx & 63;
        const float* W;
        switch (z) {
            case 0:  W = W0; break;
            case 1:  W = W1; break;
            case 2:  W = W2; break;
            default: W = W3; break;
        }
        unsigned short* T = (z < 3) ? Tqkv : To;
        const int ngbase  = (z < 3) ? z * 512 : 0;
        const int k0 = (rem & 7) * 64, n0 = (rem >> 3) * 64;
        const int r = t >> 6, c = t & 63;
#pragma unroll
        for (int rep = 0; rep < 16; ++rep) {
            const int row = rep * 4 + r;
            tile[row][c] = W[(size_t)(k0 + row) * NOUT + n0 + c];
        }
        __syncthreads();
        const int k  = k0 + c;
        const int ks = k >> 5, kk = k & 31;
#pragma unroll
        for (int rep = 0; rep < 16; ++rep) {
            const int row = rep * 4 + r;          // n within this matrix
            const int ng  = ngbase + n0 + row;
            T[((size_t)(ng >> 7) * 65536) + ks * 4096 + (ng & 127) * 32 + kk]
                = f2bf(tile[c][row]);
        }
        return;
    }
    // ---- amask: 4 u32 words (8 keys) per thread ----
    {
        const int gid  = (blk - 2304) * 256 + t;   // 0..524287
        const int w0   = gid * 4;
        const int qrow = w0 >> 10;
        const int wloc = w0 & 1023;
        const int kb0  = wloc * 2;
        int4 a0 = *(const int4*)(adj + (size_t)qrow * NN + kb0);
        int4 a1 = *(const int4*)(adj + (size_t)qrow * NN + kb0 + 4);
        uint4 m;
        m.x = (a0.x ? 0xFFFFu : 0u) | (a0.y ? 0xFFFF0000u : 0u);
        m.y = (a0.z ? 0xFFFFu : 0u) | (a0.w ? 0xFFFF0000u : 0u);
        m.z = (a1.x ? 0xFFFFu : 0u) | (a1.y ? 0xFFFF0000u : 0u);
        m.w = (a1.z ? 0xFFFFu : 0u) | (a1.w ? 0xFFFF0000u : 0u);
        *(uint4*)(amaskW + (size_t)qrow * 1024 + wloc) = m;
    }
}

// ---------------------------------------------------------------------------
// Barrier-free, LDS-free GEMM K-loop on fragment-tiled inputs (128x128).
// ---------------------------------------------------------------------------
#define GT_SETUP(Atil, Wtil)                                                   \
    const int t = threadIdx.x, wave = t >> 6, lane = t & 63;                   \
    const int quad = lane >> 4, l16 = lane & 15;                               \
    const int n0 = blockIdx.x * 128, m0 = blockIdx.y * 128;                    \
    const int wm = (wave & 1) * 64, wn = (wave >> 1) * 64;                     \
    const unsigned short* aP[4];                                               \
    const unsigned short* bP[4];                                               \
    _Pragma("unroll")                                                          \
    for (int mt = 0; mt < 4; ++mt)                                             \
        aP[mt] = Atil + (size_t)blockIdx.y * 65536                             \
               + (wm + mt * 16 + l16) * 32 + quad * 8;                         \
    _Pragma("unroll")                                                          \
    for (int nt = 0; nt < 4; ++nt)                                             \
        bP[nt] = Wtil + (size_t)blockIdx.x * 65536                             \
               + (wn + nt * 16 + l16) * 32 + quad * 8;

#define GT_LOADF(Af, Bf, NTC, ks)                                              \
    _Pragma("unroll")                                                          \
    for (int mt = 0; mt < 4; ++mt) Af[mt] = *(const bf16x8*)(aP[mt] + (ks) * 4096); \
    _Pragma("unroll")                                                          \
    for (int nt = 0; nt < NTC; ++nt) Bf[nt] = *(const bf16x8*)(bP[nt] + (ks) * 4096);

#define GT_MFMA(Af, Bf, NTC)                                                   \
    _Pragma("unroll")                                                          \
    for (int mt = 0; mt < 4; ++mt)                                             \
        _Pragma("unroll")                                                      \
        for (int nt = 0; nt < NTC; ++nt)                                       \
            acc[mt][nt] = MFMA32(Af[mt], Bf[nt], acc[mt][nt]);

#define GT_LOOP(NTC)                                                           \
    f32x4 acc[4][NTC];                                                         \
    _Pragma("unroll")                                                          \
    for (int mt = 0; mt < 4; ++mt)                                             \
        _Pragma("unroll")                                                      \
        for (int nt = 0; nt < NTC; ++nt) acc[mt][nt] = (f32x4){0.f, 0.f, 0.f, 0.f}; \
    bf16x8 aA[4], bA[NTC], aB[4], bB[NTC];                                     \
    GT_LOADF(aA, bA, NTC, 0);                                                  \
    for (int kk = 0; kk < 8; ++kk) {                                           \
        GT_LOADF(aB, bB, NTC, 2 * kk + 1);                                     \
        GT_MFMA(aA, bA, NTC);                                                  \
        if (kk < 7) { GT_LOADF(aA, bA, NTC, 2 * kk + 2); }                     \
        GT_MFMA(aB, bB, NTC);                                                  \
    }

// ---------------------------------------------------------------------------
// Fused QKV GEMM. Coalesced epilogue via per-wave LDS round-trip.
// seg0 -> q bf16 [B,H,N,64] pre-scaled by SCALE2; seg1 -> k; seg2 -> v^T.
// ---------------------------------------------------------------------------
__global__ __launch_bounds__(256, 3) void gemm_qkv(
    const unsigned short* __restrict__ Atil,
    const unsigned short* __restrict__ Wtil,
    const float* __restrict__ bq, const float* __restrict__ bk,
    const float* __restrict__ bv,
    unsigned short* __restrict__ qo, unsigned short* __restrict__ ko,
    unsigned short* __restrict__ vto)
{
    __shared__ unsigned short eps[4 * 2560];   // per-wave epilogue region (20KB)
    GT_SETUP(Atil, Wtil);
    GT_LOOP(4);

    const int seg   = n0 >> 9;           // 0:q 1:k 2:v
    const int nloc0 = n0 & 511;
    const float* bp = (seg == 0) ? bq : (seg == 1) ? bk : bv;
    unsigned short* dst3 = (seg == 0) ? qo : (seg == 1) ? ko : vto;
    const int h = (nloc0 + wn) >> 6;     // wave's 64 cols = one head

    float bias4[4];
#pragma unroll
    for (int nt = 0; nt < 4; ++nt) bias4[nt] = bp[nloc0 + wn + nt * 16 + l16];

    unsigned short* Lo = eps + wave * 2560;
#pragma unroll
    for (int mt = 0; mt < 4; ++mt) {
        if (seg < 2) {
            // region [16 m][72 d-pad], C-layout scatter -> row-coalesced out
#pragma unroll
            for (int nt = 0; nt < 4; ++nt)
#pragma unroll
                for (int r = 0; r < 4; ++r) {
                    float val = acc[mt][nt][r] + bias4[nt];
                    if (seg == 0) val *= SCALE2;
                    Lo[(quad * 4 + r) * 72 + nt * 16 + l16] = f2bf(val);
                }
#pragma unroll
            for (int pass = 0; pass < 2; ++pass) {
                const int row = pass * 8 + (lane >> 3);
                const int mg  = m0 + wm + mt * 16 + row;
                const int bb  = mg >> 11, n = mg & (NN - 1);
                bf16x8 v = *(const bf16x8*)&Lo[row * 72 + (lane & 7) * 8];
                *(bf16x8*)(dst3 + ((size_t)(bb * NH + h) * NN + n) * HDIM
                           + (lane & 7) * 8) = v;
            }
        } else {
            // region [64 d][40-pad m], transposed scatter -> d-row out
#pragma unroll
            for (int nt = 0; nt < 4; ++nt)
#pragma unroll
                for (int r = 0; r < 4; ++r) {
                    const float val = acc[mt][nt][r] + bias4[nt];
                    Lo[(nt * 16 + l16) * 40 + quad * 4 + r] = f2bf(val);
                }
            const int d  = lane;
            const int mg = m0 + wm + mt * 16;
            const int bb = mg >> 11, n = mg & (NN - 1);
            unsigned short* dr = dst3 + ((size_t)(bb * NH + h) * HDIM + d) * NN + n;
            *(bf16x8*)dr       = *(const bf16x8*)&Lo[d * 40];
            *(bf16x8*)(dr + 8) = *(const bf16x8*)&Lo[d * 40 + 8];
        }
    }
}

// ---------------------------------------------------------------------------
// O-projection GEMM: 128x64 tiles (512 blocks, 2/CU), out fp32 [8192,512]
// ---------------------------------------------------------------------------
__global__ __launch_bounds__(256, 3) void gemm_o(
    const unsigned short* __restrict__ Atil,
    const unsigned short* __restrict__ Wtil,
    const float* __restrict__ bias,
    float* __restrict__ C)
{
    const int t = threadIdx.x, wave = t >> 6, lane = t & 63;
    const int quad = lane >> 4, l16 = lane & 15;
    const int n0 = blockIdx.x * 64, m0 = blockIdx.y * 128;
    const int wm = (wave & 1) * 64, wn = (wave >> 1) * 32;
    const unsigned short* aP[4];
    const unsigned short* bP[2];
#pragma unroll
    for (int mt = 0; mt < 4; ++mt)
        aP[mt] = Atil + (size_t)blockIdx.y * 65536
               + (wm + mt * 16 + l16) * 32 + quad * 8;
#pragma unroll
    for (int nt = 0; nt < 2; ++nt)
        bP[nt] = Wtil + (size_t)(n0 >> 7) * 65536
               + ((n0 & 64) + wn + nt * 16 + l16) * 32 + quad * 8;

    GT_LOOP(2);

    float bias2[2];
#pragma unroll
    for (int nt = 0; nt < 2; ++nt) bias2[nt] = bias[n0 + wn + nt * 16 + l16];

#pragma unroll
    for (int mt = 0; mt < 4; ++mt)
#pragma unroll
        for (int nt = 0; nt < 2; ++nt) {
            const int col = n0 + wn + nt * 16 + l16;
#pragma unroll
            for (int r = 0; r < 4; ++r) {
                const int row = m0 + wm + mt * 16 + quad * 4 + r;
                C[(size_t)row * NOUT + col] = acc[mt][nt][r] + bias2[nt];
            }
        }
}

// ---------------------------------------------------------------------------
// MFMA flash attention — all-K=32 formulation via key permutation.
// v4: key-split wave pairs (v3) + counted-vmcnt pipeline (T3/T4).
// Triple-buffered K/V (3 x 16 KB), raw s_barrier per 64-key tile, and
// hand-placed s_waitcnt vmcnt(N) BEFORE the barrier so each wave's own
// DMA(t) has landed when anyone crosses; DMA(t+2) stays in flight across
// two barriers (2 tiles of compute slack, covers HBM latency). Ledger:
// each iteration issues exactly 4 VMEM ops (2 mask uint4 + 2 global_load_lds)
// between memory-clobbered asm fences, so vmcnt(4) at iter-top forces
// everything issued <= iter t-2. Iter 0 uses vmcnt(2) (prologue pinned by
// fences: [Q/masks] | DMA(0) | DMA(1)); last iter peeled with vmcnt(0).
// ---------------------------------------------------------------------------
__global__ __launch_bounds__(512, 4) void attn_mfma(
    const unsigned short* __restrict__ qg,
    const unsigned short* __restrict__ kg,
    const unsigned short* __restrict__ vt,
    const unsigned int* __restrict__ amask,   // [q][1024] u32 AND-words
    unsigned short* __restrict__ aot)
{
    // 48 KB: 3 x (K 8KB | V 8KB) triple buffer; reused afterwards for the
    // pair-reduction F region (36 KB) and epilogue Lo regions (18 KB).
    __shared__ unsigned short smem[24576];

    const int t    = threadIdx.x;
    const int wave = t >> 6;
    const int lane = t & 63;
    const int quad = lane >> 4;
    const int l16  = lane & 15;
    const int pair = wave >> 1;          // 0..3: q-rows pair*32..+31
    const int hk   = wave & 1;           // key half within each 64-key tile

    const int qt = blockIdx.x, h = blockIdx.y, b = blockIdx.z;
    const int bh = b * NH + h;
    const int q0 = qt * 128;

    const unsigned short* kbase  = kg + (size_t)bh * NN * HDIM;
    const unsigned short* vtbase = vt + (size_t)bh * HDIM * NN;

    // DMA swizzle (16B blocks): physical blk = logical blk ^ (row & 7)
    const int drow = lane >> 3;
    const int dblk = (lane & 7) ^ drow;
    // key permutation: physical LDS row p holds logical key L(p)
    const int p  = wave * 8 + drow;
    const int Lp = (p & 32) + ((p >> 2) & 3) * 8 + ((p >> 4) & 1) * 4 + (p & 3);

    // fragment-read swizzle offsets
    const int sw  = l16 & 7;
    const int bo0 = (quad ^ sw) * 8;         // K d-chunk0 (16B)
    const int bo1 = bo0 ^ 32;                // K d-chunk1

#define ATT_ISSUE(kt, Kd, Vd)                                                  \
    {                                                                          \
        const int r0 = wave * 8;                                               \
        __builtin_amdgcn_global_load_lds(                                      \
            (gas_ptr)(kbase + (size_t)((kt) * 64 + Lp) * HDIM + dblk * 8),     \
            (las_ptr)(Kd + r0 * 64), 16, 0, 0);                                \
        __builtin_amdgcn_global_load_lds(                                      \
            (gas_ptr)(vtbase + (size_t)(r0 + drow) * NN + (kt) * 64 + dblk * 8), \
            (las_ptr)(Vd + r0 * 64), 16, 0, 0);                                \
    }

    // Q B-fragments for the pair's TWO 16-row q-groups
    const int myq0 = q0 + pair * 32 + l16;        // g=0
    const int myq1 = myq0 + 16;                   // g=1
    const unsigned short* qrow0 = qg + ((size_t)bh * NN + myq0) * HDIM;
    const unsigned short* qrow1 = qg + ((size_t)bh * NN + myq1) * HDIM;
    const bf16x8 bQ0g0 = *(const bf16x8*)(qrow0 + quad * 8);
    const bf16x8 bQ1g0 = *(const bf16x8*)(qrow0 + quad * 8 + 32);
    const bf16x8 bQ0g1 = *(const bf16x8*)(qrow1 + quad * 8);
    const bf16x8 bQ1g1 = *(const bf16x8*)(qrow1 + quad * 8 + 32);

    const unsigned int* mrow0 = amask + (size_t)myq0 * 1024 + quad * 4;
    const unsigned int* mrow1 = amask + (size_t)myq1 * 1024 + quad * 4;
#define MLOAD(kt, g) (*(const uint4*)(((g) ? mrow1 : mrow0) + (kt) * 32 + hk * 16))

    bf16x8 ones8;
#pragma unroll
    for (int j = 0; j < 8; ++j) ones8[j] = (short)0x3F80;

    f32x4 O[4][2];                // [dt 16-d group][q-group]
#pragma unroll
    for (int dt = 0; dt < 4; ++dt)
#pragma unroll
        for (int g = 0; g < 2; ++g) O[dt][g] = (f32x4){0.f, 0.f, 0.f, 0.f};
    f32x4 lacc[2];
    lacc[0] = (f32x4){0.f, 0.f, 0.f, 0.f};
    lacc[1] = (f32x4){0.f, 0.f, 0.f, 0.f};

    auto tile = [&](const unsigned short* Ks, const unsigned short* Vs,
                    uint4 mwg0, uint4 mwg1) {
        // K fragments for this wave's 32-key half, read ONCE, used for 2 q-groups
        bf16x8 aK[2][2];          // [kg 16-key group][d-chunk]
#pragma unroll
        for (int kg = 0; kg < 2; ++kg) {
            const int nt = hk * 2 + kg;
            aK[kg][0] = *(const bf16x8*)&Ks[(nt * 16 + l16) * 64 + bo0];
            aK[kg][1] = *(const bf16x8*)&Ks[(nt * 16 + l16) * 64 + bo1];
        }
        bf16x8 Pt[2];
#pragma unroll
        for (int g = 0; g < 2; ++g) {
            const uint4 mw = g ? mwg1 : mwg0;
            const bf16x8 q0f = g ? bQ0g1 : bQ0g0;
            const bf16x8 q1f = g ? bQ1g1 : bQ1g0;
            union { unsigned int u[4]; bf16x8 v; } cv;
#pragma unroll
            for (int kg = 0; kg < 2; ++kg) {
                f32x4 s = (f32x4){0.f, 0.f, 0.f, 0.f};
                s = MFMA32(aK[kg][0], q0f, s);
                s = MFMA32(aK[kg][1], q1f, s);
                const float p0 = exp2f(s[0]);
                const float p1 = exp2f(s[1]);
                const float p2 = exp2f(s[2]);
                const float p3 = exp2f(s[3]);
                cv.u[kg * 2 + 0] = pack_trunc(p0, p1) & (kg ? mw.z : mw.x);
                cv.u[kg * 2 + 1] = pack_trunc(p2, p3) & (kg ? mw.w : mw.y);
            }
            Pt[g] = cv.v;
            lacc[g] = MFMA32(ones8, Pt[g], lacc[g]);
        }
#pragma unroll
        for (int dt = 0; dt < 4; ++dt) {
            bf16x8 aV = *(const bf16x8*)
                &Vs[(dt * 16 + l16) * 64 + (((hk * 4 + quad) ^ sw) * 8)];
#pragma unroll
            for (int g = 0; g < 2; ++g)
                O[dt][g] = MFMA32(aV, Pt[g], O[dt][g]);
        }
    };

    // triple-buffer rotating pointers (kept in registers, never indexed)
    unsigned short* pK0 = smem;          unsigned short* pV0 = smem + 4096;
    unsigned short* pK1 = smem + 8192;   unsigned short* pV1 = smem + 12288;
    unsigned short* pK2 = smem + 16384;  unsigned short* pV2 = smem + 20480;

    // prologue: masks(0) + Q already issued above; pin DMA(0) then DMA(1)
    uint4 m0_ = MLOAD(0, 0), m1_ = MLOAD(0, 1);
    asm volatile("" ::: "memory");
    ATT_ISSUE(0, pK0, pV0);
    asm volatile("" ::: "memory");
    ATT_ISSUE(1, pK1, pV1);

    for (int tt = 0; tt < 31; ++tt) {
        // own DMA(tt) landed (forces all but the youngest 4/2 VMEM ops)
        if (tt == 0) asm volatile("s_waitcnt vmcnt(2)" ::: "memory");
        else         asm volatile("s_waitcnt vmcnt(4)" ::: "memory");
        __builtin_amdgcn_s_barrier();   // => every wave's DMA(tt) landed
        // this iteration's 4 VMEM ops: 2 mask loads + 2 DMA (stay in flight)
        uint4 n0_ = MLOAD(tt + 1, 0), n1_ = MLOAD(tt + 1, 1);
        if (tt < 30) ATT_ISSUE(tt + 2, pK2, pV2);
        tile(pK0, pV0, m0_, m1_);
        m0_ = n0_; m1_ = n1_;
        // rotate buffers
        unsigned short* k0 = pK0; pK0 = pK1; pK1 = pK2; pK2 = k0;
        unsigned short* v0 = pV0; pV0 = pV1; pV1 = pV2; pV2 = v0;
    }
    asm volatile("s_waitcnt vmcnt(0)" ::: "memory");
    __builtin_amdgcn_s_barrier();
    tile(pK0, pV0, m0_, m1_);
    __syncthreads();   // all waves done reading K/V buffers

    // ---- cross-pair reduction: hk=1 partials -> LDS -> hk=0 accumulates ----
    // F region: [pair][lane][36 f32] (stride 36 words = 144 B, 16B-aligned)
    float* F   = (float*)smem;
    float* myF = F + ((size_t)pair * 64 + lane) * 36;
    if (hk == 1) {
#pragma unroll
        for (int dt = 0; dt < 4; ++dt)
#pragma unroll
            for (int g = 0; g < 2; ++g)
                *(f32x4*)(myF + dt * 8 + g * 4) = O[dt][g];
        myF[32] = lacc[0][0];
        myF[33] = lacc[1][0];
    }
    __syncthreads();
    float inv0 = 0.f, inv1 = 0.f;
    if (hk == 0) {
#pragma unroll
        for (int dt = 0; dt < 4; ++dt)
#pragma unroll
            for (int g = 0; g < 2; ++g) {
                const f32x4 o2 = *(const f32x4*)(myF + dt * 8 + g * 4);
                O[dt][g] += o2;
            }
        inv0 = 1.f / (lacc[0][0] + myF[32]);
        inv1 = 1.f / (lacc[1][0] + myF[33]);
    }
    __syncthreads();   // F consumed; smem reusable for Lo regions

    // ---- epilogue (hk=0 waves): O^T -> per-group LDS region -> tiled out ----
    if (hk == 0) {
#pragma unroll
        for (int g = 0; g < 2; ++g) {
            const float inv = g ? inv1 : inv0;
            unsigned short* Lo = smem + (pair * 2 + g) * 1152;
#pragma unroll
            for (int dt = 0; dt < 4; ++dt) {
                const float v0 = O[dt][g][0] * inv, v1 = O[dt][g][1] * inv;
                const float v2 = O[dt][g][2] * inv, v3 = O[dt][g][3] * inv;
                *(unsigned int*)&Lo[l16 * 72 + dt * 16 + quad * 4]     = pack_trunc(v0, v1);
                *(unsigned int*)&Lo[l16 * 72 + dt * 16 + quad * 4 + 2] = pack_trunc(v2, v3);
            }
            const int rr = lane >> 2;
            const int qq = q0 + pair * 32 + g * 16 + rr;
            const int m  = b * NN + qq;
            const int mb = m >> 7, r = m & 127;
#pragma unroll
            for (int i = 0; i < 2; ++i) {
                const int ch = (lane & 3) + 4 * i;            // 0..7 (d = ch*8)
                const int ks = h * 2 + (ch >> 2);
                bf16x8 val = *(const bf16x8*)&Lo[rr * 72 + ch * 8];
                *(bf16x8*)(aot + (size_t)mb * 65536 + ks * 4096 + r * 32 + (ch & 3) * 8) = val;
            }
        }
    }
#undef ATT_ISSUE
#undef MLOAD
}

// ---------------------------------------------------------------------------
extern "C" void kernel_launch(void* const* d_in, const int* in_sizes, int n_in,
                              void* d_out, int out_size, void* d_ws, size_t ws_size,
                              hipStream_t stream)
{
    const float* x   = (const float*)d_in[0];
    const int*   adj = (const int*)  d_in[1];
    const float* Wq  = (const float*)d_in[2];
    const float* bq  = (const float*)d_in[3];
    const float* Wk  = (const float*)d_in[4];
    const float* bk  = (const float*)d_in[5];
    const float* Wv  = (const float*)d_in[6];
    const float* bv  = (const float*)d_in[7];
    const float* Wo  = (const float*)d_in[8];
    const float* bo  = (const float*)d_in[9];
    float* out = (float*)d_out;

    const size_t qkv_elems = (size_t)NB * NH * NN * HDIM;   // 4,194,304
    unsigned short* xt    = (unsigned short*)d_ws;           // x tiled; reused as aot
    unsigned short* q     = xt   + qkv_elems;
    unsigned short* kb    = q    + qkv_elems;
    unsigned short* vtb   = kb   + qkv_elems;
    unsigned short* tWqkv = vtb  + qkv_elems;                // 1536x512 tiled
    unsigned short* tWo   = tWqkv + (size_t)3 * DD * NOUT;   // 512x512 tiled
    unsigned int*   amaskW = (unsigned int*)(tWo + (size_t)DD * NOUT);  // 8MB
    unsigned short* aot   = xt;                              // alias (xt dead after QKV)

    prep<<<dim3(4352), 256, 0, stream>>>(x, xt, Wq, Wk, Wv, Wo,
                                         tWqkv, tWo, adj, amaskW);

    gemm_qkv<<<dim3(12, 64), 256, 0, stream>>>(xt, tWqkv, bq, bk, bv, q, kb, vtb);

    attn_mfma<<<dim3(NN / 128, NH, NB), 512, 0, stream>>>(q, kb, vtb, amaskW, aot);

    gemm_o<<<dim3(8, 64), 256, 0, stream>>>(aot, tWo, bo, out);
}

// Round 5
// 190.692 us; speedup vs baseline: 1.0346x; 1.0346x over previous
//
#include <hip/hip_runtime.h>
#include <math.h>

#define NB   4
#define NN   2048
#define DD   512
#define NOUT 512
#define NH   8
#define HDIM 64

typedef __attribute__((ext_vector_type(4))) short bf16x4;
typedef __attribute__((ext_vector_type(8))) short bf16x8;
typedef __attribute__((ext_vector_type(4))) float f32x4;
#define MFMA32(a, b, c)  __builtin_amdgcn_mfma_f32_16x16x32_bf16(a, b, c, 0, 0, 0)

typedef const __attribute__((address_space(1))) unsigned int* gas_ptr;
typedef __attribute__((address_space(3))) unsigned int* las_ptr;

#define SCALE2 0.18033688f   /* 8^-1 * log2(e) */

// Fragment-tiled layout: T[blk128][kstep32][row128][32k]
//   flat = blk*65536 + ks*4096 + r*32 + kk

__device__ inline unsigned short f2bf(float f) {
    unsigned int u = __float_as_uint(f);
    u += 0x7fffu + ((u >> 16) & 1u);   // RNE
    return (unsigned short)(u >> 16);
}

// pack two fp32 -> two bf16 (truncation) in ONE v_perm
__device__ inline unsigned int pack_trunc(float lo, float hi) {
    return __builtin_amdgcn_perm(__float_as_uint(hi), __float_as_uint(lo), 0x07060302u);
}

// Raw v_exp_f32 (2^x) via the COMPILER-VISIBLE builtin. exp2f lowers to a
// denormal-fixup sequence (~4 extra VALU/cmp per call) we never need
// (|s| << 126). NOTE: must NOT be inline asm — the MFMA->VALU RAW hazard
// on CDNA is software-managed (s_nop insertion keyed on the reader being a
// recognized VALU op); an INLINEASM reader skips the hazard check and reads
// the MFMA destination early (this was round-4's 5e-2 corruption).
#if __has_builtin(__builtin_amdgcn_exp2f)
#define EXP2(x) __builtin_amdgcn_exp2f(x)
#else
#define EXP2(x) exp2f(x)
#endif

// ---------------------------------------------------------------------------
// prep: convx (x -> bf16, fragment-tiled), transW (weights -> bf16 transposed
// + tiled), amask (adj -> u32 AND-words: word w of row q = 0xFFFF per live
// key {2w,2w+1}).
// ---------------------------------------------------------------------------
__global__ __launch_bounds__(256) void prep(
    const float* __restrict__ x, unsigned short* __restrict__ xt,
    const float* __restrict__ W0, const float* __restrict__ W1,
    const float* __restrict__ W2, const float* __restrict__ W3,
    unsigned short* __restrict__ Tqkv, unsigned short* __restrict__ To,
    const int* __restrict__ adj, unsigned int* __restrict__ amaskW)
{
    const int blk = blockIdx.x;
    const int t   = threadIdx.x;

    if (blk < 2048) {                       // ---- convx -> tiled ----
        const int i = (blk * 256 + t) * 8;
        const int m = i >> 9, k = i & 511;
        float4 a = *(const float4*)(x + i);
        float4 b = *(const float4*)(x + i + 4);
        ushort4 u0, u1;
        u0.x = f2bf(a.x); u0.y = f2bf(a.y); u0.z = f2bf(a.z); u0.w = f2bf(a.w);
        u1.x = f2bf(b.x); u1.y = f2bf(b.y); u1.z = f2bf(b.z); u1.w = f2bf(b.w);
        unsigned short* dst = xt + ((size_t)(m >> 7) * 65536)
                                 + (k >> 5) * 4096 + (m & 127) * 32 + (k & 31);
        *(ushort4*)dst       = u0;
        *(ushort4*)(dst + 4) = u1;
        return;
    }
    if (blk < 2304) {                       // ---- transW -> tiled ----
        __shared__ float tile[64][65];
        const int idx = blk - 2048;
        const int z = idx >> 6, rem = idx & 63;
        const float* W;
        switch (z) {
            case 0:  W = W0; break;
            case 1:  W = W1; break;
            case 2:  W = W2; break;
            default: W = W3; break;
        }
        unsigned short* T = (z < 3) ? Tqkv : To;
        const int ngbase  = (z < 3) ? z * 512 : 0;
        const int k0 = (rem & 7) * 64, n0 = (rem >> 3) * 64;
        const int r = t >> 6, c = t & 63;
#pragma unroll
        for (int rep = 0; rep < 16; ++rep) {
            const int row = rep * 4 + r;
            tile[row][c] = W[(size_t)(k0 + row) * NOUT + n0 + c];
        }
        __syncthreads();
        const int k  = k0 + c;
        const int ks = k >> 5, kk = k & 31;
#pragma unroll
        for (int rep = 0; rep < 16; ++rep) {
            const int row = rep * 4 + r;          // n within this matrix
            const int ng  = ngbase + n0 + row;
            T[((size_t)(ng >> 7) * 65536) + ks * 4096 + (ng & 127) * 32 + kk]
                = f2bf(tile[c][row]);
        }
        return;
    }
    // ---- amask: 4 u32 words (8 keys) per thread ----
    {
        const int gid  = (blk - 2304) * 256 + t;   // 0..524287
        const int w0   = gid * 4;
        const int qrow = w0 >> 10;
        const int wloc = w0 & 1023;
        const int kb0  = wloc * 2;
        int4 a0 = *(const int4*)(adj + (size_t)qrow * NN + kb0);
        int4 a1 = *(const int4*)(adj + (size_t)qrow * NN + kb0 + 4);
        uint4 m;
        m.x = (a0.x ? 0xFFFFu : 0u) | (a0.y ? 0xFFFF0000u : 0u);
        m.y = (a0.z ? 0xFFFFu : 0u) | (a0.w ? 0xFFFF0000u : 0u);
        m.z = (a1.x ? 0xFFFFu : 0u) | (a1.y ? 0xFFFF0000u : 0u);
        m.w = (a1.z ? 0xFFFFu : 0u) | (a1.w ? 0xFFFF0000u : 0u);
        *(uint4*)(amaskW + (size_t)qrow * 1024 + wloc) = m;
    }
}

// ---------------------------------------------------------------------------
// Barrier-free, LDS-free GEMM K-loop on fragment-tiled inputs (128x128).
// T1 XCD swizzle: 8 consecutive-swz blocks share an XCD -> per-XCD working
// set (A-panel group + full B) becomes L2-resident instead of re-fetching
// the whole A matrix per XCD. nwg%8==0 for both GEMMs -> bijective.
// ---------------------------------------------------------------------------
#define GT_SETUP(Atil, Wtil)                                                   \
    const int t = threadIdx.x, wave = t >> 6, lane = t & 63;                   \
    const int quad = lane >> 4, l16 = lane & 15;                               \
    const int _orig = blockIdx.y * gridDim.x + blockIdx.x;                     \
    const int _nwg  = gridDim.x * gridDim.y;                                   \
    const int _swz  = (_orig & 7) * (_nwg >> 3) + (_orig >> 3);                \
    const int bx = _swz % gridDim.x, by = _swz / gridDim.x;                    \
    const int n0 = bx * 128, m0 = by * 128;                                    \
    const int wm = (wave & 1) * 64, wn = (wave >> 1) * 64;                     \
    const unsigned short* aP[4];                                               \
    const unsigned short* bP[4];                                               \
    _Pragma("unroll")                                                          \
    for (int mt = 0; mt < 4; ++mt)                                             \
        aP[mt] = Atil + (size_t)by * 65536                                     \
               + (wm + mt * 16 + l16) * 32 + quad * 8;                         \
    _Pragma("unroll")                                                          \
    for (int nt = 0; nt < 4; ++nt)                                             \
        bP[nt] = Wtil + (size_t)bx * 65536                                     \
               + (wn + nt * 16 + l16) * 32 + quad * 8;

#define GT_LOADF(Af, Bf, NTC, ks)                                              \
    _Pragma("unroll")                                                          \
    for (int mt = 0; mt < 4; ++mt) Af[mt] = *(const bf16x8*)(aP[mt] + (ks) * 4096); \
    _Pragma("unroll")                                                          \
    for (int nt = 0; nt < NTC; ++nt) Bf[nt] = *(const bf16x8*)(bP[nt] + (ks) * 4096);

#define GT_MFMA(Af, Bf, NTC)                                                   \
    _Pragma("unroll")                                                          \
    for (int mt = 0; mt < 4; ++mt)                                             \
        _Pragma("unroll")                                                      \
        for (int nt = 0; nt < NTC; ++nt)                                       \
            acc[mt][nt] = MFMA32(Af[mt], Bf[nt], acc[mt][nt]);

#define GT_LOOP(NTC)                                                           \
    f32x4 acc[4][NTC];                                                         \
    _Pragma("unroll")                                                          \
    for (int mt = 0; mt < 4; ++mt)                                             \
        _Pragma("unroll")                                                      \
        for (int nt = 0; nt < NTC; ++nt) acc[mt][nt] = (f32x4){0.f, 0.f, 0.f, 0.f}; \
    bf16x8 aA[4], bA[NTC], aB[4], bB[NTC];                                     \
    GT_LOADF(aA, bA, NTC, 0);                                                  \
    for (int kk = 0; kk < 8; ++kk) {                                           \
        GT_LOADF(aB, bB, NTC, 2 * kk + 1);                                     \
        GT_MFMA(aA, bA, NTC);                                                  \
        if (kk < 7) { GT_LOADF(aA, bA, NTC, 2 * kk + 2); }                     \
        GT_MFMA(aB, bB, NTC);                                                  \
    }

// ---------------------------------------------------------------------------
// Fused QKV GEMM. Coalesced epilogue via per-wave LDS round-trip.
// seg0 -> q bf16 [B,H,N,64] pre-scaled by SCALE2; seg1 -> k; seg2 -> v^T.
// ---------------------------------------------------------------------------
__global__ __launch_bounds__(256, 3) void gemm_qkv(
    const unsigned short* __restrict__ Atil,
    const unsigned short* __restrict__ Wtil,
    const float* __restrict__ bq, const float* __restrict__ bk,
    const float* __restrict__ bv,
    unsigned short* __restrict__ qo, unsigned short* __restrict__ ko,
    unsigned short* __restrict__ vto)
{
    __shared__ unsigned short eps[4 * 2560];   // per-wave epilogue region (20KB)
    GT_SETUP(Atil, Wtil);
    GT_LOOP(4);

    const int seg   = n0 >> 9;           // 0:q 1:k 2:v
    const int nloc0 = n0 & 511;
    const float* bp = (seg == 0) ? bq : (seg == 1) ? bk : bv;
    unsigned short* dst3 = (seg == 0) ? qo : (seg == 1) ? ko : vto;
    const int h = (nloc0 + wn) >> 6;     // wave's 64 cols = one head

    float bias4[4];
#pragma unroll
    for (int nt = 0; nt < 4; ++nt) bias4[nt] = bp[nloc0 + wn + nt * 16 + l16];

    unsigned short* Lo = eps + wave * 2560;
#pragma unroll
    for (int mt = 0; mt < 4; ++mt) {
        if (seg < 2) {
            // region [16 m][72 d-pad], C-layout scatter -> row-coalesced out
#pragma unroll
            for (int nt = 0; nt < 4; ++nt)
#pragma unroll
                for (int r = 0; r < 4; ++r) {
                    float val = acc[mt][nt][r] + bias4[nt];
                    if (seg == 0) val *= SCALE2;
                    Lo[(quad * 4 + r) * 72 + nt * 16 + l16] = f2bf(val);
                }
#pragma unroll
            for (int pass = 0; pass < 2; ++pass) {
                const int row = pass * 8 + (lane >> 3);
                const int mg  = m0 + wm + mt * 16 + row;
                const int bb  = mg >> 11, n = mg & (NN - 1);
                bf16x8 v = *(const bf16x8*)&Lo[row * 72 + (lane & 7) * 8];
                *(bf16x8*)(dst3 + ((size_t)(bb * NH + h) * NN + n) * HDIM
                           + (lane & 7) * 8) = v;
            }
        } else {
            // region [64 d][40-pad m], transposed scatter -> d-row out
#pragma unroll
            for (int nt = 0; nt < 4; ++nt)
#pragma unroll
                for (int r = 0; r < 4; ++r) {
                    const float val = acc[mt][nt][r] + bias4[nt];
                    Lo[(nt * 16 + l16) * 40 + quad * 4 + r] = f2bf(val);
                }
            const int d  = lane;
            const int mg = m0 + wm + mt * 16;
            const int bb = mg >> 11, n = mg & (NN - 1);
            unsigned short* dr = dst3 + ((size_t)(bb * NH + h) * HDIM + d) * NN + n;
            *(bf16x8*)dr       = *(const bf16x8*)&Lo[d * 40];
            *(bf16x8*)(dr + 8) = *(const bf16x8*)&Lo[d * 40 + 8];
        }
    }
}

// ---------------------------------------------------------------------------
// O-projection GEMM: 128x64 tiles (512 blocks, 2/CU), out fp32 [8192,512]
// ---------------------------------------------------------------------------
__global__ __launch_bounds__(256, 3) void gemm_o(
    const unsigned short* __restrict__ Atil,
    const unsigned short* __restrict__ Wtil,
    const float* __restrict__ bias,
    float* __restrict__ C)
{
    const int t = threadIdx.x, wave = t >> 6, lane = t & 63;
    const int quad = lane >> 4, l16 = lane & 15;
    const int _orig = blockIdx.y * gridDim.x + blockIdx.x;
    const int _nwg  = gridDim.x * gridDim.y;          // 512, %8==0
    const int _swz  = (_orig & 7) * (_nwg >> 3) + (_orig >> 3);
    const int bx = _swz % gridDim.x, by = _swz / gridDim.x;
    const int n0 = bx * 64, m0 = by * 128;
    const int wm = (wave & 1) * 64, wn = (wave >> 1) * 32;
    const unsigned short* aP[4];
    const unsigned short* bP[2];
#pragma unroll
    for (int mt = 0; mt < 4; ++mt)
        aP[mt] = Atil + (size_t)by * 65536
               + (wm + mt * 16 + l16) * 32 + quad * 8;
#pragma unroll
    for (int nt = 0; nt < 2; ++nt)
        bP[nt] = Wtil + (size_t)(n0 >> 7) * 65536
               + ((n0 & 64) + wn + nt * 16 + l16) * 32 + quad * 8;

    GT_LOOP(2);

    float bias2[2];
#pragma unroll
    for (int nt = 0; nt < 2; ++nt) bias2[nt] = bias[n0 + wn + nt * 16 + l16];

#pragma unroll
    for (int mt = 0; mt < 4; ++mt)
#pragma unroll
        for (int nt = 0; nt < 2; ++nt) {
            const int col = n0 + wn + nt * 16 + l16;
#pragma unroll
            for (int r = 0; r < 4; ++r) {
                const int row = m0 + wm + mt * 16 + quad * 4 + r;
                C[(size_t)row * NOUT + col] = acc[mt][nt][r] + bias2[nt];
            }
        }
}

// ---------------------------------------------------------------------------
// MFMA flash attention — all-K=32 formulation via key permutation.
// v6 = v3 (best: 61.4 us) + builtin v_exp_f32. Key-split wave pairs: 8 waves,
// 128 q/block, 64-key double-buffered phases. Wave pair p = {2p,2p+1}
// jointly owns q-rows p*32..+31; wave hk=wave&1 processes only key-chunk
// hk*32..+31 of each 64-key tile (4 K + 4 V ds_read_b128 per wave-tile).
// Partial O/l reduced across the pair once at the end via LDS.
// ---------------------------------------------------------------------------
__global__ __launch_bounds__(512, 4) void attn_mfma(
    const unsigned short* __restrict__ qg,
    const unsigned short* __restrict__ kg,
    const unsigned short* __restrict__ vt,
    const unsigned int* __restrict__ amask,   // [q][1024] u32 AND-words
    unsigned short* __restrict__ aot)
{
    // 36 KB: K/V double-buffer (32 KB) during loop; pair-reduction F +
    // epilogue Lo regions afterwards.
    __shared__ unsigned short smem[18432];
    unsigned short* Ka = smem;            // [64][64]
    unsigned short* Va = smem + 4096;
    unsigned short* Kb = smem + 8192;
    unsigned short* Vb = smem + 12288;

    const int t    = threadIdx.x;
    const int wave = t >> 6;
    const int lane = t & 63;
    const int quad = lane >> 4;
    const int l16  = lane & 15;
    const int pair = wave >> 1;          // 0..3: q-rows pair*32..+31
    const int hk   = wave & 1;           // key half within each 64-key tile

    const int qt = blockIdx.x, h = blockIdx.y, b = blockIdx.z;
    const int bh = b * NH + h;
    const int q0 = qt * 128;

    const unsigned short* kbase  = kg + (size_t)bh * NN * HDIM;
    const unsigned short* vtbase = vt + (size_t)bh * HDIM * NN;

    // DMA swizzle (16B blocks): physical blk = logical blk ^ (row & 7)
    const int drow = lane >> 3;
    const int dblk = (lane & 7) ^ drow;
    // key permutation: physical LDS row p holds logical key L(p)
    const int p  = wave * 8 + drow;
    const int Lp = (p & 32) + ((p >> 2) & 3) * 8 + ((p >> 4) & 1) * 4 + (p & 3);

    // fragment-read swizzle offsets
    const int sw  = l16 & 7;
    const int bo0 = (quad ^ sw) * 8;         // K d-chunk0 (16B)
    const int bo1 = bo0 ^ 32;                // K d-chunk1

#define ATT_ISSUE(kt, Kd, Vd)                                                  \
    {                                                                          \
        const int r0 = wave * 8;                                               \
        __builtin_amdgcn_global_load_lds(                                      \
            (gas_ptr)(kbase + (size_t)((kt) * 64 + Lp) * HDIM + dblk * 8),     \
            (las_ptr)(Kd + r0 * 64), 16, 0, 0);                                \
        __builtin_amdgcn_global_load_lds(                                      \
            (gas_ptr)(vtbase + (size_t)(r0 + drow) * NN + (kt) * 64 + dblk * 8), \
            (las_ptr)(Vd + r0 * 64), 16, 0, 0);                                \
    }

    // Q B-fragments for the pair's TWO 16-row q-groups
    const int myq0 = q0 + pair * 32 + l16;        // g=0
    const int myq1 = myq0 + 16;                   // g=1
    const unsigned short* qrow0 = qg + ((size_t)bh * NN + myq0) * HDIM;
    const unsigned short* qrow1 = qg + ((size_t)bh * NN + myq1) * HDIM;
    const bf16x8 bQ0g0 = *(const bf16x8*)(qrow0 + quad * 8);
    const bf16x8 bQ1g0 = *(const bf16x8*)(qrow0 + quad * 8 + 32);
    const bf16x8 bQ0g1 = *(const bf16x8*)(qrow1 + quad * 8);
    const bf16x8 bQ1g1 = *(const bf16x8*)(qrow1 + quad * 8 + 32);

    const unsigned int* mrow0 = amask + (size_t)myq0 * 1024 + quad * 4;
    const unsigned int* mrow1 = amask + (size_t)myq1 * 1024 + quad * 4;
#define MLOAD(kt, g) (*(const uint4*)(((g) ? mrow1 : mrow0) + (kt) * 32 + hk * 16))

    bf16x8 ones8;
#pragma unroll
    for (int j = 0; j < 8; ++j) ones8[j] = (short)0x3F80;

    f32x4 O[4][2];                // [dt 16-d group][q-group]
#pragma unroll
    for (int dt = 0; dt < 4; ++dt)
#pragma unroll
        for (int g = 0; g < 2; ++g) O[dt][g] = (f32x4){0.f, 0.f, 0.f, 0.f};
    f32x4 lacc[2];
    lacc[0] = (f32x4){0.f, 0.f, 0.f, 0.f};
    lacc[1] = (f32x4){0.f, 0.f, 0.f, 0.f};

    auto tile = [&](const unsigned short* Ks, const unsigned short* Vs,
                    uint4 mwg0, uint4 mwg1) {
        // K fragments for this wave's 32-key half, read ONCE, used for 2 q-groups
        bf16x8 aK[2][2];          // [kg 16-key group][d-chunk]
#pragma unroll
        for (int kg = 0; kg < 2; ++kg) {
            const int nt = hk * 2 + kg;
            aK[kg][0] = *(const bf16x8*)&Ks[(nt * 16 + l16) * 64 + bo0];
            aK[kg][1] = *(const bf16x8*)&Ks[(nt * 16 + l16) * 64 + bo1];
        }
        bf16x8 Pt[2];
#pragma unroll
        for (int g = 0; g < 2; ++g) {
            const uint4 mw = g ? mwg1 : mwg0;
            const bf16x8 q0f = g ? bQ0g1 : bQ0g0;
            const bf16x8 q1f = g ? bQ1g1 : bQ1g0;
            union { unsigned int u[4]; bf16x8 v; } cv;
#pragma unroll
            for (int kg = 0; kg < 2; ++kg) {
                f32x4 s = (f32x4){0.f, 0.f, 0.f, 0.f};
                s = MFMA32(aK[kg][0], q0f, s);
                s = MFMA32(aK[kg][1], q1f, s);
                const float p0 = EXP2(s[0]);
                const float p1 = EXP2(s[1]);
                const float p2 = EXP2(s[2]);
                const float p3 = EXP2(s[3]);
                cv.u[kg * 2 + 0] = pack_trunc(p0, p1) & (kg ? mw.z : mw.x);
                cv.u[kg * 2 + 1] = pack_trunc(p2, p3) & (kg ? mw.w : mw.y);
            }
            Pt[g] = cv.v;
            lacc[g] = MFMA32(ones8, Pt[g], lacc[g]);
        }
#pragma unroll
        for (int dt = 0; dt < 4; ++dt) {
            bf16x8 aV = *(const bf16x8*)
                &Vs[(dt * 16 + l16) * 64 + (((hk * 4 + quad) ^ sw) * 8)];
#pragma unroll
            for (int g = 0; g < 2; ++g)
                O[dt][g] = MFMA32(aV, Pt[g], O[dt][g]);
        }
    };

    uint4 mA0 = MLOAD(0, 0), mA1 = MLOAD(0, 1);
    uint4 mB0, mB1;
    ATT_ISSUE(0, Ka, Va);
    for (int kk = 0; kk < 16; ++kk) {
        __syncthreads();
        ATT_ISSUE(2 * kk + 1, Kb, Vb);
        mB0 = MLOAD(2 * kk + 1, 0); mB1 = MLOAD(2 * kk + 1, 1);
        tile(Ka, Va, mA0, mA1);
        __syncthreads();
        if (kk < 15) {
            ATT_ISSUE(2 * kk + 2, Ka, Va);
            mA0 = MLOAD(2 * kk + 2, 0); mA1 = MLOAD(2 * kk + 2, 1);
        }
        tile(Kb, Vb, mB0, mB1);
    }
    __syncthreads();   // all waves done reading K/V buffers

    // ---- cross-pair reduction: hk=1 partials -> LDS -> hk=0 accumulates ----
    // F region: [pair][lane][36 f32] (stride 36 words = 144 B, 16B-aligned)
    float* F   = (float*)smem;
    float* myF = F + ((size_t)pair * 64 + lane) * 36;
    if (hk == 1) {
#pragma unroll
        for (int dt = 0; dt < 4; ++dt)
#pragma unroll
            for (int g = 0; g < 2; ++g)
                *(f32x4*)(myF + dt * 8 + g * 4) = O[dt][g];
        myF[32] = lacc[0][0];
        myF[33] = lacc[1][0];
    }
    __syncthreads();
    float inv0 = 0.f, inv1 = 0.f;
    if (hk == 0) {
#pragma unroll
        for (int dt = 0; dt < 4; ++dt)
#pragma unroll
            for (int g = 0; g < 2; ++g) {
                const f32x4 o2 = *(const f32x4*)(myF + dt * 8 + g * 4);
                O[dt][g] += o2;
            }
        inv0 = 1.f / (lacc[0][0] + myF[32]);
        inv1 = 1.f / (lacc[1][0] + myF[33]);
    }
    __syncthreads();   // F consumed; smem reusable for Lo regions

    // ---- epilogue (hk=0 waves): O^T -> per-group LDS region -> tiled out ----
    if (hk == 0) {
#pragma unroll
        for (int g = 0; g < 2; ++g) {
            const float inv = g ? inv1 : inv0;
            unsigned short* Lo = smem + (pair * 2 + g) * 1152;
#pragma unroll
            for (int dt = 0; dt < 4; ++dt) {
                const float v0 = O[dt][g][0] * inv, v1 = O[dt][g][1] * inv;
                const float v2 = O[dt][g][2] * inv, v3 = O[dt][g][3] * inv;
                *(unsigned int*)&Lo[l16 * 72 + dt * 16 + quad * 4]     = pack_trunc(v0, v1);
                *(unsigned int*)&Lo[l16 * 72 + dt * 16 + quad * 4 + 2] = pack_trunc(v2, v3);
            }
            const int rr = lane >> 2;
            const int qq = q0 + pair * 32 + g * 16 + rr;
            const int m  = b * NN + qq;
            const int mb = m >> 7, r = m & 127;
#pragma unroll
            for (int i = 0; i < 2; ++i) {
                const int ch = (lane & 3) + 4 * i;            // 0..7 (d = ch*8)
                const int ks = h * 2 + (ch >> 2);
                bf16x8 val = *(const bf16x8*)&Lo[rr * 72 + ch * 8];
                *(bf16x8*)(aot + (size_t)mb * 65536 + ks * 4096 + r * 32 + (ch & 3) * 8) = val;
            }
        }
    }
#undef ATT_ISSUE
#undef MLOAD
}

// ---------------------------------------------------------------------------
extern "C" void kernel_launch(void* const* d_in, const int* in_sizes, int n_in,
                              void* d_out, int out_size, void* d_ws, size_t ws_size,
                              hipStream_t stream)
{
    const float* x   = (const float*)d_in[0];
    const int*   adj = (const int*)  d_in[1];
    const float* Wq  = (const float*)d_in[2];
    const float* bq  = (const float*)d_in[3];
    const float* Wk  = (const float*)d_in[4];
    const float* bk  = (const float*)d_in[5];
    const float* Wv  = (const float*)d_in[6];
    const float* bv  = (const float*)d_in[7];
    const float* Wo  = (const float*)d_in[8];
    const float* bo  = (const float*)d_in[9];
    float* out = (float*)d_out;

    const size_t qkv_elems = (size_t)NB * NH * NN * HDIM;   // 4,194,304
    unsigned short* xt    = (unsigned short*)d_ws;           // x tiled; reused as aot
    unsigned short* q     = xt   + qkv_elems;
    unsigned short* kb    = q    + qkv_elems;
    unsigned short* vtb   = kb   + qkv_elems;
    unsigned short* tWqkv = vtb  + qkv_elems;                // 1536x512 tiled
    unsigned short* tWo   = tWqkv + (size_t)3 * DD * NOUT;   // 512x512 tiled
    unsigned int*   amaskW = (unsigned int*)(tWo + (size_t)DD * NOUT);  // 8MB
    unsigned short* aot   = xt;                              // alias (xt dead after QKV)

    prep<<<dim3(4352), 256, 0, stream>>>(x, xt, Wq, Wk, Wv, Wo,
                                         tWqkv, tWo, adj, amaskW);

    gemm_qkv<<<dim3(12, 64), 256, 0, stream>>>(xt, tWqkv, bq, bk, bv, q, kb, vtb);

    attn_mfma<<<dim3(NN / 128, NH, NB), 512, 0, stream>>>(q, kb, vtb, amaskW, aot);

    gemm_o<<<dim3(8, 64), 256, 0, stream>>>(aot, tWo, bo, out);
}

// Round 6
// 189.173 us; speedup vs baseline: 1.0429x; 1.0080x over previous
//
#include <hip/hip_runtime.h>
#include <math.h>

#define NB   4
#define NN   2048
#define DD   512
#define NOUT 512
#define NH   8
#define HDIM 64

typedef __attribute__((ext_vector_type(4))) short bf16x4;
typedef __attribute__((ext_vector_type(8))) short bf16x8;
typedef __attribute__((ext_vector_type(4))) float f32x4;
#define MFMA32(a, b, c)  __builtin_amdgcn_mfma_f32_16x16x32_bf16(a, b, c, 0, 0, 0)

typedef const __attribute__((address_space(1))) unsigned int* gas_ptr;
typedef __attribute__((address_space(3))) unsigned int* las_ptr;

#define SCALE2 0.18033688f   /* 8^-1 * log2(e) */

// Fragment-tiled layout: T[blk128][kstep32][row128][32k]
//   flat = blk*65536 + ks*4096 + r*32 + kk

__device__ inline unsigned short f2bf(float f) {
    unsigned int u = __float_as_uint(f);
    u += 0x7fffu + ((u >> 16) & 1u);   // RNE
    return (unsigned short)(u >> 16);
}

// pack two fp32 -> two bf16 (truncation) in ONE v_perm
__device__ inline unsigned int pack_trunc(float lo, float hi) {
    return __builtin_amdgcn_perm(__float_as_uint(hi), __float_as_uint(lo), 0x07060302u);
}

// Raw v_exp_f32 (2^x) via the COMPILER-VISIBLE builtin (round-5 win: VALU
// busy halved vs OCML exp2f). Must NOT be inline asm: MFMA->VALU RAW hazard
// is software-managed and skipped for INLINEASM readers (round-4 corruption).
#if __has_builtin(__builtin_amdgcn_exp2f)
#define EXP2(x) __builtin_amdgcn_exp2f(x)
#else
#define EXP2(x) exp2f(x)
#endif

// ---------------------------------------------------------------------------
// prep: convx (x -> bf16, fragment-tiled), transW (weights -> bf16 transposed
// + tiled), amask (adj -> u32 AND-words: word w of row q = 0xFFFF per live
// key {2w,2w+1}).
// ---------------------------------------------------------------------------
__global__ __launch_bounds__(256) void prep(
    const float* __restrict__ x, unsigned short* __restrict__ xt,
    const float* __restrict__ W0, const float* __restrict__ W1,
    const float* __restrict__ W2, const float* __restrict__ W3,
    unsigned short* __restrict__ Tqkv, unsigned short* __restrict__ To,
    const int* __restrict__ adj, unsigned int* __restrict__ amaskW)
{
    const int blk = blockIdx.x;
    const int t   = threadIdx.x;

    if (blk < 2048) {                       // ---- convx -> tiled ----
        const int i = (blk * 256 + t) * 8;
        const int m = i >> 9, k = i & 511;
        float4 a = *(const float4*)(x + i);
        float4 b = *(const float4*)(x + i + 4);
        ushort4 u0, u1;
        u0.x = f2bf(a.x); u0.y = f2bf(a.y); u0.z = f2bf(a.z); u0.w = f2bf(a.w);
        u1.x = f2bf(b.x); u1.y = f2bf(b.y); u1.z = f2bf(b.z); u1.w = f2bf(b.w);
        unsigned short* dst = xt + ((size_t)(m >> 7) * 65536)
                                 + (k >> 5) * 4096 + (m & 127) * 32 + (k & 31);
        *(ushort4*)dst       = u0;
        *(ushort4*)(dst + 4) = u1;
        return;
    }
    if (blk < 2304) {                       // ---- transW -> tiled ----
        __shared__ float tile[64][65];
        const int idx = blk - 2048;
        const int z = idx >> 6, rem = idx & 63;
        const float* W;
        switch (z) {
            case 0:  W = W0; break;
            case 1:  W = W1; break;
            case 2:  W = W2; break;
            default: W = W3; break;
        }
        unsigned short* T = (z < 3) ? Tqkv : To;
        const int ngbase  = (z < 3) ? z * 512 : 0;
        const int k0 = (rem & 7) * 64, n0 = (rem >> 3) * 64;
        const int r = t >> 6, c = t & 63;
#pragma unroll
        for (int rep = 0; rep < 16; ++rep) {
            const int row = rep * 4 + r;
            tile[row][c] = W[(size_t)(k0 + row) * NOUT + n0 + c];
        }
        __syncthreads();
        const int k  = k0 + c;
        const int ks = k >> 5, kk = k & 31;
#pragma unroll
        for (int rep = 0; rep < 16; ++rep) {
            const int row = rep * 4 + r;          // n within this matrix
            const int ng  = ngbase + n0 + row;
            T[((size_t)(ng >> 7) * 65536) + ks * 4096 + (ng & 127) * 32 + kk]
                = f2bf(tile[c][row]);
        }
        return;
    }
    // ---- amask: 4 u32 words (8 keys) per thread ----
    {
        const int gid  = (blk - 2304) * 256 + t;   // 0..524287
        const int w0   = gid * 4;
        const int qrow = w0 >> 10;
        const int wloc = w0 & 1023;
        const int kb0  = wloc * 2;
        int4 a0 = *(const int4*)(adj + (size_t)qrow * NN + kb0);
        int4 a1 = *(const int4*)(adj + (size_t)qrow * NN + kb0 + 4);
        uint4 m;
        m.x = (a0.x ? 0xFFFFu : 0u) | (a0.y ? 0xFFFF0000u : 0u);
        m.y = (a0.z ? 0xFFFFu : 0u) | (a0.w ? 0xFFFF0000u : 0u);
        m.z = (a1.x ? 0xFFFFu : 0u) | (a1.y ? 0xFFFF0000u : 0u);
        m.w = (a1.z ? 0xFFFFu : 0u) | (a1.w ? 0xFFFF0000u : 0u);
        *(uint4*)(amaskW + (size_t)qrow * 1024 + wloc) = m;
    }
}

// ---------------------------------------------------------------------------
// Barrier-free, LDS-free GEMM K-loop on fragment-tiled inputs (128x128).
// (XCD swizzle REVERTED: r5 showed +6-7us on the GEMM side vs the stable
// 130us non-attn baseline of r0-r3 — linear dispatch order already had the
// better locality.)
// ---------------------------------------------------------------------------
#define GT_SETUP(Atil, Wtil)                                                   \
    const int t = threadIdx.x, wave = t >> 6, lane = t & 63;                   \
    const int quad = lane >> 4, l16 = lane & 15;                               \
    const int n0 = blockIdx.x * 128, m0 = blockIdx.y * 128;                    \
    const int wm = (wave & 1) * 64, wn = (wave >> 1) * 64;                     \
    const unsigned short* aP[4];                                               \
    const unsigned short* bP[4];                                               \
    _Pragma("unroll")                                                          \
    for (int mt = 0; mt < 4; ++mt)                                             \
        aP[mt] = Atil + (size_t)blockIdx.y * 65536                             \
               + (wm + mt * 16 + l16) * 32 + quad * 8;                         \
    _Pragma("unroll")                                                          \
    for (int nt = 0; nt < 4; ++nt)                                             \
        bP[nt] = Wtil + (size_t)blockIdx.x * 65536                             \
               + (wn + nt * 16 + l16) * 32 + quad * 8;

#define GT_LOADF(Af, Bf, NTC, ks)                                              \
    _Pragma("unroll")                                                          \
    for (int mt = 0; mt < 4; ++mt) Af[mt] = *(const bf16x8*)(aP[mt] + (ks) * 4096); \
    _Pragma("unroll")                                                          \
    for (int nt = 0; nt < NTC; ++nt) Bf[nt] = *(const bf16x8*)(bP[nt] + (ks) * 4096);

#define GT_MFMA(Af, Bf, NTC)                                                   \
    _Pragma("unroll")                                                          \
    for (int mt = 0; mt < 4; ++mt)                                             \
        _Pragma("unroll")                                                      \
        for (int nt = 0; nt < NTC; ++nt)                                       \
            acc[mt][nt] = MFMA32(Af[mt], Bf[nt], acc[mt][nt]);

#define GT_LOOP(NTC)                                                           \
    f32x4 acc[4][NTC];                                                         \
    _Pragma("unroll")                                                          \
    for (int mt = 0; mt < 4; ++mt)                                             \
        _Pragma("unroll")                                                      \
        for (int nt = 0; nt < NTC; ++nt) acc[mt][nt] = (f32x4){0.f, 0.f, 0.f, 0.f}; \
    bf16x8 aA[4], bA[NTC], aB[4], bB[NTC];                                     \
    GT_LOADF(aA, bA, NTC, 0);                                                  \
    for (int kk = 0; kk < 8; ++kk) {                                           \
        GT_LOADF(aB, bB, NTC, 2 * kk + 1);                                     \
        GT_MFMA(aA, bA, NTC);                                                  \
        if (kk < 7) { GT_LOADF(aA, bA, NTC, 2 * kk + 2); }                     \
        GT_MFMA(aB, bB, NTC);                                                  \
    }

// ---------------------------------------------------------------------------
// Fused QKV GEMM. Coalesced epilogue via per-wave LDS round-trip.
// seg0 -> q bf16 [B,H,N,64] pre-scaled by SCALE2; seg1 -> k; seg2 -> v^T.
// ---------------------------------------------------------------------------
__global__ __launch_bounds__(256, 3) void gemm_qkv(
    const unsigned short* __restrict__ Atil,
    const unsigned short* __restrict__ Wtil,
    const float* __restrict__ bq, const float* __restrict__ bk,
    const float* __restrict__ bv,
    unsigned short* __restrict__ qo, unsigned short* __restrict__ ko,
    unsigned short* __restrict__ vto)
{
    __shared__ unsigned short eps[4 * 2560];   // per-wave epilogue region (20KB)
    GT_SETUP(Atil, Wtil);
    GT_LOOP(4);

    const int seg   = n0 >> 9;           // 0:q 1:k 2:v
    const int nloc0 = n0 & 511;
    const float* bp = (seg == 0) ? bq : (seg == 1) ? bk : bv;
    unsigned short* dst3 = (seg == 0) ? qo : (seg == 1) ? ko : vto;
    const int h = (nloc0 + wn) >> 6;     // wave's 64 cols = one head

    float bias4[4];
#pragma unroll
    for (int nt = 0; nt < 4; ++nt) bias4[nt] = bp[nloc0 + wn + nt * 16 + l16];

    unsigned short* Lo = eps + wave * 2560;
#pragma unroll
    for (int mt = 0; mt < 4; ++mt) {
        if (seg < 2) {
            // region [16 m][72 d-pad], C-layout scatter -> row-coalesced out
#pragma unroll
            for (int nt = 0; nt < 4; ++nt)
#pragma unroll
                for (int r = 0; r < 4; ++r) {
                    float val = acc[mt][nt][r] + bias4[nt];
                    if (seg == 0) val *= SCALE2;
                    Lo[(quad * 4 + r) * 72 + nt * 16 + l16] = f2bf(val);
                }
#pragma unroll
            for (int pass = 0; pass < 2; ++pass) {
                const int row = pass * 8 + (lane >> 3);
                const int mg  = m0 + wm + mt * 16 + row;
                const int bb  = mg >> 11, n = mg & (NN - 1);
                bf16x8 v = *(const bf16x8*)&Lo[row * 72 + (lane & 7) * 8];
                *(bf16x8*)(dst3 + ((size_t)(bb * NH + h) * NN + n) * HDIM
                           + (lane & 7) * 8) = v;
            }
        } else {
            // region [64 d][40-pad m], transposed scatter -> d-row out
#pragma unroll
            for (int nt = 0; nt < 4; ++nt)
#pragma unroll
                for (int r = 0; r < 4; ++r) {
                    const float val = acc[mt][nt][r] + bias4[nt];
                    Lo[(nt * 16 + l16) * 40 + quad * 4 + r] = f2bf(val);
                }
            const int d  = lane;
            const int mg = m0 + wm + mt * 16;
            const int bb = mg >> 11, n = mg & (NN - 1);
            unsigned short* dr = dst3 + ((size_t)(bb * NH + h) * HDIM + d) * NN + n;
            *(bf16x8*)dr       = *(const bf16x8*)&Lo[d * 40];
            *(bf16x8*)(dr + 8) = *(const bf16x8*)&Lo[d * 40 + 8];
        }
    }
}

// ---------------------------------------------------------------------------
// O-projection GEMM: 128x64 tiles (512 blocks, 2/CU), out fp32 [8192,512]
// ---------------------------------------------------------------------------
__global__ __launch_bounds__(256, 3) void gemm_o(
    const unsigned short* __restrict__ Atil,
    const unsigned short* __restrict__ Wtil,
    const float* __restrict__ bias,
    float* __restrict__ C)
{
    const int t = threadIdx.x, wave = t >> 6, lane = t & 63;
    const int quad = lane >> 4, l16 = lane & 15;
    const int n0 = blockIdx.x * 64, m0 = blockIdx.y * 128;
    const int wm = (wave & 1) * 64, wn = (wave >> 1) * 32;
    const unsigned short* aP[4];
    const unsigned short* bP[2];
#pragma unroll
    for (int mt = 0; mt < 4; ++mt)
        aP[mt] = Atil + (size_t)blockIdx.y * 65536
               + (wm + mt * 16 + l16) * 32 + quad * 8;
#pragma unroll
    for (int nt = 0; nt < 2; ++nt)
        bP[nt] = Wtil + (size_t)(n0 >> 7) * 65536
               + ((n0 & 64) + wn + nt * 16 + l16) * 32 + quad * 8;

    GT_LOOP(2);

    float bias2[2];
#pragma unroll
    for (int nt = 0; nt < 2; ++nt) bias2[nt] = bias[n0 + wn + nt * 16 + l16];

#pragma unroll
    for (int mt = 0; mt < 4; ++mt)
#pragma unroll
        for (int nt = 0; nt < 2; ++nt) {
            const int col = n0 + wn + nt * 16 + l16;
#pragma unroll
            for (int r = 0; r < 4; ++r) {
                const int row = m0 + wm + mt * 16 + quad * 4 + r;
                C[(size_t)row * NOUT + col] = acc[mt][nt][r] + bias2[nt];
            }
        }
}

// ---------------------------------------------------------------------------
// MFMA flash attention v7: 64q-per-wave key-split.
// r5 accounting: LDS-read demand (20.5us) > VALU (16.6) > MFMA (15.4), all
// ~serialized by barrier lockstep (sum ~= wall 53.4us). LDS amplification =
// 128q / q-per-wave. This version: 4 waves x 256 thr, each wave owns
// 64 q-rows (4 q-groups) x one 32-key half -> 8 ds_read_b128 per wave-tile
// serve 64q => block LDS reads halve (32/tile vs 64). MFMA & VALU per-q
// unchanged. Occupancy 8 waves/CU (2/SIMD) but per-wave ILP doubles (4
// independent q-group chains). Pair = wave>>1 (q 0-63 / 64-127), hk = wave&1.
// ---------------------------------------------------------------------------
__global__ __launch_bounds__(256, 2) void attn_mfma(
    const unsigned short* __restrict__ qg,
    const unsigned short* __restrict__ kg,
    const unsigned short* __restrict__ vt,
    const unsigned int* __restrict__ amask,   // [q][1024] u32 AND-words
    unsigned short* __restrict__ aot)
{
    // 36 KB: K/V double-buffer (32 KB) during loop; pair-reduction F
    // (2 pairs x 64 lanes x 68 f32 = 34.8 KB) + epilogue Lo regions after.
    __shared__ unsigned short smem[18432];
    unsigned short* Ka = smem;            // [64][64]
    unsigned short* Va = smem + 4096;
    unsigned short* Kb = smem + 8192;
    unsigned short* Vb = smem + 12288;

    const int t    = threadIdx.x;
    const int wave = t >> 6;             // 0..3
    const int lane = t & 63;
    const int quad = lane >> 4;
    const int l16  = lane & 15;
    const int pair = wave >> 1;          // 0..1: q-rows pair*64..+63
    const int hk   = wave & 1;           // key half within each 64-key tile

    const int qt = blockIdx.x, h = blockIdx.y, b = blockIdx.z;
    const int bh = b * NH + h;
    const int q0 = qt * 128;

    const unsigned short* kbase  = kg + (size_t)bh * NN * HDIM;
    const unsigned short* vtbase = vt + (size_t)bh * HDIM * NN;

    // DMA swizzle (16B blocks): physical blk = logical blk ^ (row & 7)
    const int drow = lane >> 3;
    const int dblk = (lane & 7) ^ drow;
    // key permutation: physical LDS row p holds logical key L(p).
    // Each wave now stages 16 rows: p0 = wave*16+drow and p1 = p0+8.
    const int p0_ = wave * 16 + drow;
    const int p1_ = p0_ + 8;
    const int Lp0 = (p0_ & 32) + ((p0_ >> 2) & 3) * 8 + ((p0_ >> 4) & 1) * 4 + (p0_ & 3);
    const int Lp1 = (p1_ & 32) + ((p1_ >> 2) & 3) * 8 + ((p1_ >> 4) & 1) * 4 + (p1_ & 3);

    // fragment-read swizzle offsets
    const int sw  = l16 & 7;
    const int bo0 = (quad ^ sw) * 8;         // K d-chunk0 (16B)
    const int bo1 = bo0 ^ 32;                // K d-chunk1

#define ATT_ISSUE(kt, Kd, Vd)                                                  \
    {                                                                          \
        const int r0 = wave * 16;                                              \
        __builtin_amdgcn_global_load_lds(                                      \
            (gas_ptr)(kbase + (size_t)((kt) * 64 + Lp0) * HDIM + dblk * 8),    \
            (las_ptr)(Kd + r0 * 64), 16, 0, 0);                                \
        __builtin_amdgcn_global_load_lds(                                      \
            (gas_ptr)(kbase + (size_t)((kt) * 64 + Lp1) * HDIM + dblk * 8),    \
            (las_ptr)(Kd + (r0 + 8) * 64), 16, 0, 0);                          \
        __builtin_amdgcn_global_load_lds(                                      \
            (gas_ptr)(vtbase + (size_t)(r0 + drow) * NN + (kt) * 64 + dblk * 8), \
            (las_ptr)(Vd + r0 * 64), 16, 0, 0);                                \
        __builtin_amdgcn_global_load_lds(                                      \
            (gas_ptr)(vtbase + (size_t)(r0 + 8 + drow) * NN + (kt) * 64 + dblk * 8), \
            (las_ptr)(Vd + (r0 + 8) * 64), 16, 0, 0);                          \
    }

    // Q B-fragments + mask rows for the wave's FOUR 16-row q-groups
    bf16x8 bQ0[4], bQ1[4];
    const unsigned int* mrow[4];
#pragma unroll
    for (int g = 0; g < 4; ++g) {
        const int myq = q0 + pair * 64 + g * 16 + l16;
        const unsigned short* qr = qg + ((size_t)bh * NN + myq) * HDIM;
        bQ0[g] = *(const bf16x8*)(qr + quad * 8);
        bQ1[g] = *(const bf16x8*)(qr + quad * 8 + 32);
        mrow[g] = amask + (size_t)myq * 1024 + quad * 4;
    }
#define MLOAD(kt, g) (*(const uint4*)(mrow[g] + (kt) * 32 + hk * 16))

    bf16x8 ones8;
#pragma unroll
    for (int j = 0; j < 8; ++j) ones8[j] = (short)0x3F80;

    f32x4 O[4][4];                // [dt 16-d group][q-group]
#pragma unroll
    for (int dt = 0; dt < 4; ++dt)
#pragma unroll
        for (int g = 0; g < 4; ++g) O[dt][g] = (f32x4){0.f, 0.f, 0.f, 0.f};
    f32x4 lacc[4];
#pragma unroll
    for (int g = 0; g < 4; ++g) lacc[g] = (f32x4){0.f, 0.f, 0.f, 0.f};

    // masks passed by value (named vars, no local-array pointer -> no scratch)
    auto tile = [&](const unsigned short* Ks, const unsigned short* Vs,
                    uint4 w0, uint4 w1, uint4 w2, uint4 w3) {
        // K fragments for this wave's 32-key half, read ONCE, used for 4 q-groups
        bf16x8 aK[2][2];          // [kg 16-key group][d-chunk]
#pragma unroll
        for (int kg = 0; kg < 2; ++kg) {
            const int nt = hk * 2 + kg;
            aK[kg][0] = *(const bf16x8*)&Ks[(nt * 16 + l16) * 64 + bo0];
            aK[kg][1] = *(const bf16x8*)&Ks[(nt * 16 + l16) * 64 + bo1];
        }
        bf16x8 Pt[4];
#pragma unroll
        for (int g = 0; g < 4; ++g) {
            const uint4 mw = (g == 0) ? w0 : (g == 1) ? w1 : (g == 2) ? w2 : w3;
            union { unsigned int u[4]; bf16x8 v; } cv;
#pragma unroll
            for (int kg = 0; kg < 2; ++kg) {
                f32x4 s = (f32x4){0.f, 0.f, 0.f, 0.f};
                s = MFMA32(aK[kg][0], bQ0[g], s);
                s = MFMA32(aK[kg][1], bQ1[g], s);
                const float p0 = EXP2(s[0]);
                const float p1 = EXP2(s[1]);
                const float p2 = EXP2(s[2]);
                const float p3 = EXP2(s[3]);
                cv.u[kg * 2 + 0] = pack_trunc(p0, p1) & (kg ? mw.z : mw.x);
                cv.u[kg * 2 + 1] = pack_trunc(p2, p3) & (kg ? mw.w : mw.y);
            }
            Pt[g] = cv.v;
            lacc[g] = MFMA32(ones8, Pt[g], lacc[g]);
        }
#pragma unroll
        for (int dt = 0; dt < 4; ++dt) {
            bf16x8 aV = *(const bf16x8*)
                &Vs[(dt * 16 + l16) * 64 + (((hk * 4 + quad) ^ sw) * 8)];
#pragma unroll
            for (int g = 0; g < 4; ++g)
                O[dt][g] = MFMA32(aV, Pt[g], O[dt][g]);
        }
    };

    uint4 mA0 = MLOAD(0, 0), mA1 = MLOAD(0, 1), mA2 = MLOAD(0, 2), mA3 = MLOAD(0, 3);
    uint4 mB0, mB1, mB2, mB3;
    ATT_ISSUE(0, Ka, Va);
    for (int kk = 0; kk < 16; ++kk) {
        __syncthreads();
        ATT_ISSUE(2 * kk + 1, Kb, Vb);
        mB0 = MLOAD(2 * kk + 1, 0); mB1 = MLOAD(2 * kk + 1, 1);
        mB2 = MLOAD(2 * kk + 1, 2); mB3 = MLOAD(2 * kk + 1, 3);
        tile(Ka, Va, mA0, mA1, mA2, mA3);
        __syncthreads();
        if (kk < 15) {
            ATT_ISSUE(2 * kk + 2, Ka, Va);
            mA0 = MLOAD(2 * kk + 2, 0); mA1 = MLOAD(2 * kk + 2, 1);
            mA2 = MLOAD(2 * kk + 2, 2); mA3 = MLOAD(2 * kk + 2, 3);
        }
        tile(Kb, Vb, mB0, mB1, mB2, mB3);
    }
    __syncthreads();   // all waves done reading K/V buffers

    // ---- cross-pair reduction: hk=1 partials -> LDS -> hk=0 accumulates ----
    // F region: [pair][lane][68 f32] (64 O + 4 lacc; stride 272B, 16B-aligned)
    float* F   = (float*)smem;
    float* myF = F + ((size_t)(pair * 64 + lane)) * 68;
    if (hk == 1) {
#pragma unroll
        for (int dt = 0; dt < 4; ++dt)
#pragma unroll
            for (int g = 0; g < 4; ++g)
                *(f32x4*)(myF + dt * 16 + g * 4) = O[dt][g];
#pragma unroll
        for (int g = 0; g < 4; ++g) myF[64 + g] = lacc[g][0];
    }
    __syncthreads();
    float inv[4] = {0.f, 0.f, 0.f, 0.f};
    if (hk == 0) {
#pragma unroll
        for (int dt = 0; dt < 4; ++dt)
#pragma unroll
            for (int g = 0; g < 4; ++g) {
                const f32x4 o2 = *(const f32x4*)(myF + dt * 16 + g * 4);
                O[dt][g] += o2;
            }
#pragma unroll
        for (int g = 0; g < 4; ++g)
            inv[g] = 1.f / (lacc[g][0] + myF[64 + g]);
    }
    __syncthreads();   // F consumed; smem reusable for Lo regions

    // ---- epilogue (hk=0 waves): O^T -> per-group LDS region -> tiled out ----
    if (hk == 0) {
#pragma unroll
        for (int g = 0; g < 4; ++g) {
            unsigned short* Lo = smem + (pair * 4 + g) * 1152;
#pragma unroll
            for (int dt = 0; dt < 4; ++dt) {
                const float v0 = O[dt][g][0] * inv[g], v1 = O[dt][g][1] * inv[g];
                const float v2 = O[dt][g][2] * inv[g], v3 = O[dt][g][3] * inv[g];
                *(unsigned int*)&Lo[l16 * 72 + dt * 16 + quad * 4]     = pack_trunc(v0, v1);
                *(unsigned int*)&Lo[l16 * 72 + dt * 16 + quad * 4 + 2] = pack_trunc(v2, v3);
            }
            const int rr = lane >> 2;
            const int qq = q0 + pair * 64 + g * 16 + rr;
            const int m  = b * NN + qq;
            const int mb = m >> 7, r = m & 127;
#pragma unroll
            for (int i = 0; i < 2; ++i) {
                const int ch = (lane & 3) + 4 * i;            // 0..7 (d = ch*8)
                const int ks = h * 2 + (ch >> 2);
                bf16x8 val = *(const bf16x8*)&Lo[rr * 72 + ch * 8];
                *(bf16x8*)(aot + (size_t)mb * 65536 + ks * 4096 + r * 32 + (ch & 3) * 8) = val;
            }
        }
    }
#undef ATT_ISSUE
#undef MLOAD
}

// ---------------------------------------------------------------------------
extern "C" void kernel_launch(void* const* d_in, const int* in_sizes, int n_in,
                              void* d_out, int out_size, void* d_ws, size_t ws_size,
                              hipStream_t stream)
{
    const float* x   = (const float*)d_in[0];
    const int*   adj = (const int*)  d_in[1];
    const float* Wq  = (const float*)d_in[2];
    const float* bq  = (const float*)d_in[3];
    const float* Wk  = (const float*)d_in[4];
    const float* bk  = (const float*)d_in[5];
    const float* Wv  = (const float*)d_in[6];
    const float* bv  = (const float*)d_in[7];
    const float* Wo  = (const float*)d_in[8];
    const float* bo  = (const float*)d_in[9];
    float* out = (float*)d_out;

    const size_t qkv_elems = (size_t)NB * NH * NN * HDIM;   // 4,194,304
    unsigned short* xt    = (unsigned short*)d_ws;           // x tiled; reused as aot
    unsigned short* q     = xt   + qkv_elems;
    unsigned short* kb    = q    + qkv_elems;
    unsigned short* vtb   = kb   + qkv_elems;
    unsigned short* tWqkv = vtb  + qkv_elems;                // 1536x512 tiled
    unsigned short* tWo   = tWqkv + (size_t)3 * DD * NOUT;   // 512x512 tiled
    unsigned int*   amaskW = (unsigned int*)(tWo + (size_t)DD * NOUT);  // 8MB
    unsigned short* aot   = xt;                              // alias (xt dead after QKV)

    prep<<<dim3(4352), 256, 0, stream>>>(x, xt, Wq, Wk, Wv, Wo,
                                         tWqkv, tWo, adj, amaskW);

    gemm_qkv<<<dim3(12, 64), 256, 0, stream>>>(xt, tWqkv, bq, bk, bv, q, kb, vtb);

    attn_mfma<<<dim3(NN / 128, NH, NB), 256, 0, stream>>>(q, kb, vtb, amaskW, aot);

    gemm_o<<<dim3(8, 64), 256, 0, stream>>>(aot, tWo, bo, out);
}

// Round 7
// 172.607 us; speedup vs baseline: 1.1430x; 1.0960x over previous
//
#include <hip/hip_runtime.h>
#include <math.h>

#define NB   4
#define NN   2048
#define DD   512
#define NOUT 512
#define NH   8
#define HDIM 64

typedef __attribute__((ext_vector_type(4))) short bf16x4;
typedef __attribute__((ext_vector_type(8))) short bf16x8;
typedef __attribute__((ext_vector_type(4))) float f32x4;
#define MFMA32(a, b, c)  __builtin_amdgcn_mfma_f32_16x16x32_bf16(a, b, c, 0, 0, 0)

typedef const __attribute__((address_space(1))) unsigned int* gas_ptr;
typedef __attribute__((address_space(3))) unsigned int* las_ptr;

#define SCALE2 0.18033688f   /* 8^-1 * log2(e) */

// Fragment-tiled layout: T[blk128][kstep32][row128][32k]
//   flat = blk*65536 + ks*4096 + r*32 + kk

__device__ inline unsigned short f2bf(float f) {
    unsigned int u = __float_as_uint(f);
    u += 0x7fffu + ((u >> 16) & 1u);   // RNE
    return (unsigned short)(u >> 16);
}

// pack two fp32 -> two bf16 (truncation) in ONE v_perm
__device__ inline unsigned int pack_trunc(float lo, float hi) {
    return __builtin_amdgcn_perm(__float_as_uint(hi), __float_as_uint(lo), 0x07060302u);
}

// Raw v_exp_f32 (2^x) via the COMPILER-VISIBLE builtin (round-5 win: VALU
// busy halved vs OCML exp2f). Must NOT be inline asm: MFMA->VALU RAW hazard
// is software-managed and skipped for INLINEASM readers (round-4 corruption).
#if __has_builtin(__builtin_amdgcn_exp2f)
#define EXP2(x) __builtin_amdgcn_exp2f(x)
#else
#define EXP2(x) exp2f(x)
#endif

// LDS 16B-block swizzle for staged GEMM tiles: involution (XORs bits 3-5
// into bits 0-2, disjoint) => stage source block SWZB(d) into LDS block d,
// read global block g at LDS block SWZB(g). Spreads a quad-group's 16
// ds_read_b128 lanes across all 8 bank-slots (2-way aliasing = free, m136).
#define SWZB(g) ((g) ^ (((g) >> 3) & 7))

// ---------------------------------------------------------------------------
// prep: convx (x -> bf16, fragment-tiled), transW (weights -> bf16 transposed
// + tiled), amask (adj -> u32 AND-words: word w of row q = 0xFFFF per live
// key {2w,2w+1}).
// ---------------------------------------------------------------------------
__global__ __launch_bounds__(256) void prep(
    const float* __restrict__ x, unsigned short* __restrict__ xt,
    const float* __restrict__ W0, const float* __restrict__ W1,
    const float* __restrict__ W2, const float* __restrict__ W3,
    unsigned short* __restrict__ Tqkv, unsigned short* __restrict__ To,
    const int* __restrict__ adj, unsigned int* __restrict__ amaskW)
{
    const int blk = blockIdx.x;
    const int t   = threadIdx.x;

    if (blk < 2048) {                       // ---- convx -> tiled ----
        const int i = (blk * 256 + t) * 8;
        const int m = i >> 9, k = i & 511;
        float4 a = *(const float4*)(x + i);
        float4 b = *(const float4*)(x + i + 4);
        ushort4 u0, u1;
        u0.x = f2bf(a.x); u0.y = f2bf(a.y); u0.z = f2bf(a.z); u0.w = f2bf(a.w);
        u1.x = f2bf(b.x); u1.y = f2bf(b.y); u1.z = f2bf(b.z); u1.w = f2bf(b.w);
        unsigned short* dst = xt + ((size_t)(m >> 7) * 65536)
                                 + (k >> 5) * 4096 + (m & 127) * 32 + (k & 31);
        *(ushort4*)dst       = u0;
        *(ushort4*)(dst + 4) = u1;
        return;
    }
    if (blk < 2304) {                       // ---- transW -> tiled ----
        __shared__ float tile[64][65];
        const int idx = blk - 2048;
        const int z = idx >> 6, rem = idx & 63;
        const float* W;
        switch (z) {
            case 0:  W = W0; break;
            case 1:  W = W1; break;
            case 2:  W = W2; break;
            default: W = W3; break;
        }
        unsigned short* T = (z < 3) ? Tqkv : To;
        const int ngbase  = (z < 3) ? z * 512 : 0;
        const int k0 = (rem & 7) * 64, n0 = (rem >> 3) * 64;
        const int r = t >> 6, c = t & 63;
#pragma unroll
        for (int rep = 0; rep < 16; ++rep) {
            const int row = rep * 4 + r;
            tile[row][c] = W[(size_t)(k0 + row) * NOUT + n0 + c];
        }
        __syncthreads();
        const int k  = k0 + c;
        const int ks = k >> 5, kk = k & 31;
#pragma unroll
        for (int rep = 0; rep < 16; ++rep) {
            const int row = rep * 4 + r;          // n within this matrix
            const int ng  = ngbase + n0 + row;
            T[((size_t)(ng >> 7) * 65536) + ks * 4096 + (ng & 127) * 32 + kk]
                = f2bf(tile[c][row]);
        }
        return;
    }
    // ---- amask: 4 u32 words (8 keys) per thread ----
    {
        const int gid  = (blk - 2304) * 256 + t;   // 0..524287
        const int w0   = gid * 4;
        const int qrow = w0 >> 10;
        const int wloc = w0 & 1023;
        const int kb0  = wloc * 2;
        int4 a0 = *(const int4*)(adj + (size_t)qrow * NN + kb0);
        int4 a1 = *(const int4*)(adj + (size_t)qrow * NN + kb0 + 4);
        uint4 m;
        m.x = (a0.x ? 0xFFFFu : 0u) | (a0.y ? 0xFFFF0000u : 0u);
        m.y = (a0.z ? 0xFFFFu : 0u) | (a0.w ? 0xFFFF0000u : 0u);
        m.z = (a1.x ? 0xFFFFu : 0u) | (a1.y ? 0xFFFF0000u : 0u);
        m.w = (a1.z ? 0xFFFFu : 0u) | (a1.w ? 0xFFFF0000u : 0u);
        *(uint4*)(amaskW + (size_t)qrow * 1024 + wloc) = m;
    }
}

// ---------------------------------------------------------------------------
// Staged GEMM (m97 structure): global_load_lds double-buffered K-loop.
// Each kstep's A/B tile is CONTIGUOUS in the fragment-tiled layout (8 KB /
// 4 KB), so staging is 3-4 gload_lds ops per wave with the SWZB bank swizzle
// applied on the (per-lane) global source; LDS dest stays linear as the HW
// requires. Readers fetch fragment block gf at LDS block SWZB(gf).
// 2 barriers per 2 ksteps (v0-attn / m97 pattern).
// ---------------------------------------------------------------------------
#define GTS_STAGE(ks, Ab, Bb, NB16)                                            \
    {                                                                          \
        const unsigned short* As_ = Asrc + (ks) * 4096;                        \
        const unsigned short* Bs_ = Bsrc + (ks) * 4096;                        \
        __builtin_amdgcn_global_load_lds(                                      \
            (gas_ptr)(As_ + (wave * 64 + lswz) * 8),                           \
            (las_ptr)((Ab) + wave * 512), 16, 0, 0);                           \
        __builtin_amdgcn_global_load_lds(                                      \
            (gas_ptr)(As_ + (256 + wave * 64 + lswz) * 8),                     \
            (las_ptr)((Ab) + 2048 + wave * 512), 16, 0, 0);                    \
        __builtin_amdgcn_global_load_lds(                                      \
            (gas_ptr)(Bs_ + (wave * 64 + lswz) * 8),                           \
            (las_ptr)((Bb) + wave * 512), 16, 0, 0);                           \
        if ((NB16) == 512)                                                     \
            __builtin_amdgcn_global_load_lds(                                  \
                (gas_ptr)(Bs_ + (256 + wave * 64 + lswz) * 8),                 \
                (las_ptr)((Bb) + 2048 + wave * 512), 16, 0, 0);                \
    }

#define GT_MFMA(Af, Bf, NTC)                                                   \
    _Pragma("unroll")                                                          \
    for (int mt = 0; mt < 4; ++mt)                                             \
        _Pragma("unroll")                                                      \
        for (int nt = 0; nt < NTC; ++nt)                                       \
            acc[mt][nt] = MFMA32(Af[mt], Bf[nt], acc[mt][nt]);

#define GTS_FRAGS(Ab, Bb, NTC)                                                 \
    bf16x8 aF[4], bF[NTC];                                                     \
    _Pragma("unroll")                                                          \
    for (int mt = 0; mt < 4; ++mt) aF[mt] = *(const bf16x8*)&(Ab)[aOff[mt]];   \
    _Pragma("unroll")                                                          \
    for (int nt = 0; nt < NTC; ++nt) bF[nt] = *(const bf16x8*)&(Bb)[bOff[nt]];

#define GTS_LOOP(NTC, NB16, sA0, sB0, sA1, sB1)                                \
    const int lswz = lane ^ ((lane >> 3) & 7);                                 \
    int aOff[4], bOff[NTC];                                                    \
    _Pragma("unroll")                                                          \
    for (int mt = 0; mt < 4; ++mt)                                             \
        aOff[mt] = SWZB((wm + mt * 16 + l16) * 4 + quad) * 8;                  \
    _Pragma("unroll")                                                          \
    for (int nt = 0; nt < NTC; ++nt)                                           \
        bOff[nt] = SWZB((wn + nt * 16 + l16) * 4 + quad) * 8;                  \
    f32x4 acc[4][NTC];                                                         \
    _Pragma("unroll")                                                          \
    for (int mt = 0; mt < 4; ++mt)                                             \
        _Pragma("unroll")                                                      \
        for (int nt = 0; nt < NTC; ++nt) acc[mt][nt] = (f32x4){0.f, 0.f, 0.f, 0.f}; \
    GTS_STAGE(0, sA0, sB0, NB16);                                              \
    for (int kk = 0; kk < 8; ++kk) {                                           \
        __syncthreads();                                                       \
        GTS_STAGE(2 * kk + 1, sA1, sB1, NB16);                                 \
        { GTS_FRAGS(sA0, sB0, NTC); GT_MFMA(aF, bF, NTC); }                    \
        __syncthreads();                                                       \
        if (kk < 7) GTS_STAGE(2 * kk + 2, sA0, sB0, NB16);                     \
        { GTS_FRAGS(sA1, sB1, NTC); GT_MFMA(aF, bF, NTC); }                    \
    }

// ---------------------------------------------------------------------------
// Fused QKV GEMM (staged). Coalesced epilogue via per-wave LDS round-trip
// (aliased onto the staging buffers after a barrier).
// seg0 -> q bf16 [B,H,N,64] pre-scaled by SCALE2; seg1 -> k; seg2 -> v^T.
// ---------------------------------------------------------------------------
__global__ __launch_bounds__(256, 3) void gemm_qkv(
    const unsigned short* __restrict__ Atil,
    const unsigned short* __restrict__ Wtil,
    const float* __restrict__ bq, const float* __restrict__ bk,
    const float* __restrict__ bv,
    unsigned short* __restrict__ qo, unsigned short* __restrict__ ko,
    unsigned short* __restrict__ vto)
{
    __shared__ unsigned short smem[16384];   // A0|B0|A1|B1 (32 KB), eps alias
    unsigned short* sA0 = smem;
    unsigned short* sB0 = smem + 4096;
    unsigned short* sA1 = smem + 8192;
    unsigned short* sB1 = smem + 12288;

    const int t = threadIdx.x, wave = t >> 6, lane = t & 63;
    const int quad = lane >> 4, l16 = lane & 15;
    const int n0 = blockIdx.x * 128, m0 = blockIdx.y * 128;
    const int wm = (wave & 1) * 64, wn = (wave >> 1) * 64;
    const unsigned short* Asrc = Atil + (size_t)blockIdx.y * 65536;
    const unsigned short* Bsrc = Wtil + (size_t)blockIdx.x * 65536;

    GTS_LOOP(4, 512, sA0, sB0, sA1, sB1);

    const int seg   = n0 >> 9;           // 0:q 1:k 2:v
    const int nloc0 = n0 & 511;
    const float* bp = (seg == 0) ? bq : (seg == 1) ? bk : bv;
    unsigned short* dst3 = (seg == 0) ? qo : (seg == 1) ? ko : vto;
    const int h = (nloc0 + wn) >> 6;     // wave's 64 cols = one head

    float bias4[4];
#pragma unroll
    for (int nt = 0; nt < 4; ++nt) bias4[nt] = bp[nloc0 + wn + nt * 16 + l16];

    __syncthreads();                     // staging reads done; alias eps
    unsigned short* Lo = smem + wave * 2560;
#pragma unroll
    for (int mt = 0; mt < 4; ++mt) {
        if (seg < 2) {
            // region [16 m][72 d-pad], C-layout scatter -> row-coalesced out
#pragma unroll
            for (int nt = 0; nt < 4; ++nt)
#pragma unroll
                for (int r = 0; r < 4; ++r) {
                    float val = acc[mt][nt][r] + bias4[nt];
                    if (seg == 0) val *= SCALE2;
                    Lo[(quad * 4 + r) * 72 + nt * 16 + l16] = f2bf(val);
                }
#pragma unroll
            for (int pass = 0; pass < 2; ++pass) {
                const int row = pass * 8 + (lane >> 3);
                const int mg  = m0 + wm + mt * 16 + row;
                const int bb  = mg >> 11, n = mg & (NN - 1);
                bf16x8 v = *(const bf16x8*)&Lo[row * 72 + (lane & 7) * 8];
                *(bf16x8*)(dst3 + ((size_t)(bb * NH + h) * NN + n) * HDIM
                           + (lane & 7) * 8) = v;
            }
        } else {
            // region [64 d][40-pad m], transposed scatter -> d-row out
#pragma unroll
            for (int nt = 0; nt < 4; ++nt)
#pragma unroll
                for (int r = 0; r < 4; ++r) {
                    const float val = acc[mt][nt][r] + bias4[nt];
                    Lo[(nt * 16 + l16) * 40 + quad * 4 + r] = f2bf(val);
                }
            const int d  = lane;
            const int mg = m0 + wm + mt * 16;
            const int bb = mg >> 11, n = mg & (NN - 1);
            unsigned short* dr = dst3 + ((size_t)(bb * NH + h) * HDIM + d) * NN + n;
            *(bf16x8*)dr       = *(const bf16x8*)&Lo[d * 40];
            *(bf16x8*)(dr + 8) = *(const bf16x8*)&Lo[d * 40 + 8];
        }
    }
}

// ---------------------------------------------------------------------------
// O-projection GEMM (staged): 128x64 tiles, out fp32 [8192,512]
// ---------------------------------------------------------------------------
__global__ __launch_bounds__(256, 3) void gemm_o(
    const unsigned short* __restrict__ Atil,
    const unsigned short* __restrict__ Wtil,
    const float* __restrict__ bias,
    float* __restrict__ C)
{
    __shared__ unsigned short smem[12288];   // A0(8K)|B0(4K)|A1(8K)|B1(4K)
    unsigned short* sA0 = smem;
    unsigned short* sB0 = smem + 4096;
    unsigned short* sA1 = smem + 6144;
    unsigned short* sB1 = smem + 10240;

    const int t = threadIdx.x, wave = t >> 6, lane = t & 63;
    const int quad = lane >> 4, l16 = lane & 15;
    const int n0 = blockIdx.x * 64, m0 = blockIdx.y * 128;
    const int wm = (wave & 1) * 64, wn = (wave >> 1) * 32;
    const unsigned short* Asrc = Atil + (size_t)blockIdx.y * 65536;
    const unsigned short* Bsrc = Wtil + (size_t)(n0 >> 7) * 65536 + (n0 & 64) * 32;

    GTS_LOOP(2, 256, sA0, sB0, sA1, sB1);

    float bias2[2];
#pragma unroll
    for (int nt = 0; nt < 2; ++nt) bias2[nt] = bias[n0 + wn + nt * 16 + l16];

#pragma unroll
    for (int mt = 0; mt < 4; ++mt)
#pragma unroll
        for (int nt = 0; nt < 2; ++nt) {
            const int col = n0 + wn + nt * 16 + l16;
#pragma unroll
            for (int r = 0; r < 4; ++r) {
                const int row = m0 + wm + mt * 16 + quad * 4 + r;
                C[(size_t)row * NOUT + col] = acc[mt][nt][r] + bias2[nt];
            }
        }
}

// ---------------------------------------------------------------------------
// MFMA flash attention — all-K=32 formulation via key permutation.
// v6 (PROVEN 53.4us, round 5): key-split wave pairs, 8 waves, 128 q/block,
// 64-key double-buffered phases, builtin v_exp_f32. Wave pair p = {2p,2p+1}
// jointly owns q-rows p*32..+31; wave hk=wave&1 processes only key-chunk
// hk*32..+31 of each 64-key tile (4 K + 4 V ds_read_b128 per wave-tile).
// Partial O/l reduced across the pair once at the end via LDS.
// (r6's 64q/wave variant regressed: occupancy 19% lost more to latency than
// the halved LDS reads gained.)
// ---------------------------------------------------------------------------
__global__ __launch_bounds__(512, 4) void attn_mfma(
    const unsigned short* __restrict__ qg,
    const unsigned short* __restrict__ kg,
    const unsigned short* __restrict__ vt,
    const unsigned int* __restrict__ amask,   // [q][1024] u32 AND-words
    unsigned short* __restrict__ aot)
{
    // 36 KB: K/V double-buffer (32 KB) during loop; pair-reduction F +
    // epilogue Lo regions afterwards.
    __shared__ unsigned short smem[18432];
    unsigned short* Ka = smem;            // [64][64]
    unsigned short* Va = smem + 4096;
    unsigned short* Kb = smem + 8192;
    unsigned short* Vb = smem + 12288;

    const int t    = threadIdx.x;
    const int wave = t >> 6;
    const int lane = t & 63;
    const int quad = lane >> 4;
    const int l16  = lane & 15;
    const int pair = wave >> 1;          // 0..3: q-rows pair*32..+31
    const int hk   = wave & 1;           // key half within each 64-key tile

    const int qt = blockIdx.x, h = blockIdx.y, b = blockIdx.z;
    const int bh = b * NH + h;
    const int q0 = qt * 128;

    const unsigned short* kbase  = kg + (size_t)bh * NN * HDIM;
    const unsigned short* vtbase = vt + (size_t)bh * HDIM * NN;

    // DMA swizzle (16B blocks): physical blk = logical blk ^ (row & 7)
    const int drow = lane >> 3;
    const int dblk = (lane & 7) ^ drow;
    // key permutation: physical LDS row p holds logical key L(p)
    const int p  = wave * 8 + drow;
    const int Lp = (p & 32) + ((p >> 2) & 3) * 8 + ((p >> 4) & 1) * 4 + (p & 3);

    // fragment-read swizzle offsets
    const int sw  = l16 & 7;
    const int bo0 = (quad ^ sw) * 8;         // K d-chunk0 (16B)
    const int bo1 = bo0 ^ 32;                // K d-chunk1

#define ATT_ISSUE(kt, Kd, Vd)                                                  \
    {                                                                          \
        const int r0 = wave * 8;                                               \
        __builtin_amdgcn_global_load_lds(                                      \
            (gas_ptr)(kbase + (size_t)((kt) * 64 + Lp) * HDIM + dblk * 8),     \
            (las_ptr)(Kd + r0 * 64), 16, 0, 0);                                \
        __builtin_amdgcn_global_load_lds(                                      \
            (gas_ptr)(vtbase + (size_t)(r0 + drow) * NN + (kt) * 64 + dblk * 8), \
            (las_ptr)(Vd + r0 * 64), 16, 0, 0);                                \
    }

    // Q B-fragments for the pair's TWO 16-row q-groups
    const int myq0 = q0 + pair * 32 + l16;        // g=0
    const int myq1 = myq0 + 16;                   // g=1
    const unsigned short* qrow0 = qg + ((size_t)bh * NN + myq0) * HDIM;
    const unsigned short* qrow1 = qg + ((size_t)bh * NN + myq1) * HDIM;
    const bf16x8 bQ0g0 = *(const bf16x8*)(qrow0 + quad * 8);
    const bf16x8 bQ1g0 = *(const bf16x8*)(qrow0 + quad * 8 + 32);
    const bf16x8 bQ0g1 = *(const bf16x8*)(qrow1 + quad * 8);
    const bf16x8 bQ1g1 = *(const bf16x8*)(qrow1 + quad * 8 + 32);

    const unsigned int* mrow0 = amask + (size_t)myq0 * 1024 + quad * 4;
    const unsigned int* mrow1 = amask + (size_t)myq1 * 1024 + quad * 4;
#define MLOAD(kt, g) (*(const uint4*)(((g) ? mrow1 : mrow0) + (kt) * 32 + hk * 16))

    bf16x8 ones8;
#pragma unroll
    for (int j = 0; j < 8; ++j) ones8[j] = (short)0x3F80;

    f32x4 O[4][2];                // [dt 16-d group][q-group]
#pragma unroll
    for (int dt = 0; dt < 4; ++dt)
#pragma unroll
        for (int g = 0; g < 2; ++g) O[dt][g] = (f32x4){0.f, 0.f, 0.f, 0.f};
    f32x4 lacc[2];
    lacc[0] = (f32x4){0.f, 0.f, 0.f, 0.f};
    lacc[1] = (f32x4){0.f, 0.f, 0.f, 0.f};

    auto tile = [&](const unsigned short* Ks, const unsigned short* Vs,
                    uint4 mwg0, uint4 mwg1) {
        // K fragments for this wave's 32-key half, read ONCE, used for 2 q-groups
        bf16x8 aK[2][2];          // [kg 16-key group][d-chunk]
#pragma unroll
        for (int kg = 0; kg < 2; ++kg) {
            const int nt = hk * 2 + kg;
            aK[kg][0] = *(const bf16x8*)&Ks[(nt * 16 + l16) * 64 + bo0];
            aK[kg][1] = *(const bf16x8*)&Ks[(nt * 16 + l16) * 64 + bo1];
        }
        bf16x8 Pt[2];
#pragma unroll
        for (int g = 0; g < 2; ++g) {
            const uint4 mw = g ? mwg1 : mwg0;
            const bf16x8 q0f = g ? bQ0g1 : bQ0g0;
            const bf16x8 q1f = g ? bQ1g1 : bQ1g0;
            union { unsigned int u[4]; bf16x8 v; } cv;
#pragma unroll
            for (int kg = 0; kg < 2; ++kg) {
                f32x4 s = (f32x4){0.f, 0.f, 0.f, 0.f};
                s = MFMA32(aK[kg][0], q0f, s);
                s = MFMA32(aK[kg][1], q1f, s);
                const float p0 = EXP2(s[0]);
                const float p1 = EXP2(s[1]);
                const float p2 = EXP2(s[2]);
                const float p3 = EXP2(s[3]);
                cv.u[kg * 2 + 0] = pack_trunc(p0, p1) & (kg ? mw.z : mw.x);
                cv.u[kg * 2 + 1] = pack_trunc(p2, p3) & (kg ? mw.w : mw.y);
            }
            Pt[g] = cv.v;
            lacc[g] = MFMA32(ones8, Pt[g], lacc[g]);
        }
#pragma unroll
        for (int dt = 0; dt < 4; ++dt) {
            bf16x8 aV = *(const bf16x8*)
                &Vs[(dt * 16 + l16) * 64 + (((hk * 4 + quad) ^ sw) * 8)];
#pragma unroll
            for (int g = 0; g < 2; ++g)
                O[dt][g] = MFMA32(aV, Pt[g], O[dt][g]);
        }
    };

    uint4 mA0 = MLOAD(0, 0), mA1 = MLOAD(0, 1);
    uint4 mB0, mB1;
    ATT_ISSUE(0, Ka, Va);
    for (int kk = 0; kk < 16; ++kk) {
        __syncthreads();
        ATT_ISSUE(2 * kk + 1, Kb, Vb);
        mB0 = MLOAD(2 * kk + 1, 0); mB1 = MLOAD(2 * kk + 1, 1);
        tile(Ka, Va, mA0, mA1);
        __syncthreads();
        if (kk < 15) {
            ATT_ISSUE(2 * kk + 2, Ka, Va);
            mA0 = MLOAD(2 * kk + 2, 0); mA1 = MLOAD(2 * kk + 2, 1);
        }
        tile(Kb, Vb, mB0, mB1);
    }
    __syncthreads();   // all waves done reading K/V buffers

    // ---- cross-pair reduction: hk=1 partials -> LDS -> hk=0 accumulates ----
    // F region: [pair][lane][36 f32] (stride 36 words = 144 B, 16B-aligned)
    float* F   = (float*)smem;
    float* myF = F + ((size_t)pair * 64 + lane) * 36;
    if (hk == 1) {
#pragma unroll
        for (int dt = 0; dt < 4; ++dt)
#pragma unroll
            for (int g = 0; g < 2; ++g)
                *(f32x4*)(myF + dt * 8 + g * 4) = O[dt][g];
        myF[32] = lacc[0][0];
        myF[33] = lacc[1][0];
    }
    __syncthreads();
    float inv0 = 0.f, inv1 = 0.f;
    if (hk == 0) {
#pragma unroll
        for (int dt = 0; dt < 4; ++dt)
#pragma unroll
            for (int g = 0; g < 2; ++g) {
                const f32x4 o2 = *(const f32x4*)(myF + dt * 8 + g * 4);
                O[dt][g] += o2;
            }
        inv0 = 1.f / (lacc[0][0] + myF[32]);
        inv1 = 1.f / (lacc[1][0] + myF[33]);
    }
    __syncthreads();   // F consumed; smem reusable for Lo regions

    // ---- epilogue (hk=0 waves): O^T -> per-group LDS region -> tiled out ----
    if (hk == 0) {
#pragma unroll
        for (int g = 0; g < 2; ++g) {
            const float inv = g ? inv1 : inv0;
            unsigned short* Lo = smem + (pair * 2 + g) * 1152;
#pragma unroll
            for (int dt = 0; dt < 4; ++dt) {
                const float v0 = O[dt][g][0] * inv, v1 = O[dt][g][1] * inv;
                const float v2 = O[dt][g][2] * inv, v3 = O[dt][g][3] * inv;
                *(unsigned int*)&Lo[l16 * 72 + dt * 16 + quad * 4]     = pack_trunc(v0, v1);
                *(unsigned int*)&Lo[l16 * 72 + dt * 16 + quad * 4 + 2] = pack_trunc(v2, v3);
            }
            const int rr = lane >> 2;
            const int qq = q0 + pair * 32 + g * 16 + rr;
            const int m  = b * NN + qq;
            const int mb = m >> 7, r = m & 127;
#pragma unroll
            for (int i = 0; i < 2; ++i) {
                const int ch = (lane & 3) + 4 * i;            // 0..7 (d = ch*8)
                const int ks = h * 2 + (ch >> 2);
                bf16x8 val = *(const bf16x8*)&Lo[rr * 72 + ch * 8];
                *(bf16x8*)(aot + (size_t)mb * 65536 + ks * 4096 + r * 32 + (ch & 3) * 8) = val;
            }
        }
    }
#undef ATT_ISSUE
#undef MLOAD
}

// ---------------------------------------------------------------------------
extern "C" void kernel_launch(void* const* d_in, const int* in_sizes, int n_in,
                              void* d_out, int out_size, void* d_ws, size_t ws_size,
                              hipStream_t stream)
{
    const float* x   = (const float*)d_in[0];
    const int*   adj = (const int*)  d_in[1];
    const float* Wq  = (const float*)d_in[2];
    const float* bq  = (const float*)d_in[3];
    const float* Wk  = (const float*)d_in[4];
    const float* bk  = (const float*)d_in[5];
    const float* Wv  = (const float*)d_in[6];
    const float* bv  = (const float*)d_in[7];
    const float* Wo  = (const float*)d_in[8];
    const float* bo  = (const float*)d_in[9];
    float* out = (float*)d_out;

    const size_t qkv_elems = (size_t)NB * NH * NN * HDIM;   // 4,194,304
    unsigned short* xt    = (unsigned short*)d_ws;           // x tiled; reused as aot
    unsigned short* q     = xt   + qkv_elems;
    unsigned short* kb    = q    + qkv_elems;
    unsigned short* vtb   = kb   + qkv_elems;
    unsigned short* tWqkv = vtb  + qkv_elems;                // 1536x512 tiled
    unsigned short* tWo   = tWqkv + (size_t)3 * DD * NOUT;   // 512x512 tiled
    unsigned int*   amaskW = (unsigned int*)(tWo + (size_t)DD * NOUT);  // 8MB
    unsigned short* aot   = xt;                              // alias (xt dead after QKV)

    prep<<<dim3(4352), 256, 0, stream>>>(x, xt, Wq, Wk, Wv, Wo,
                                         tWqkv, tWo, adj, amaskW);

    gemm_qkv<<<dim3(12, 64), 256, 0, stream>>>(xt, tWqkv, bq, bk, bv, q, kb, vtb);

    attn_mfma<<<dim3(NN / 128, NH, NB), 512, 0, stream>>>(q, kb, vtb, amaskW, aot);

    gemm_o<<<dim3(8, 64), 256, 0, stream>>>(aot, tWo, bo, out);
}